// Round 7
// baseline (9550.948 us; speedup 1.0000x reference)
//
#include <hip/hip_runtime.h>
#include <cstdint>
#include <cstddef>

typedef unsigned long long ull;

#define N_PTS  32768
#define NP1    2048
#define NSAMP1 32
#define NP2    512
#define NSAMP2 64
#define NCELL  4096

// ---------------- prep: xyz = points - [x,y,0], SoA ----------------
__global__ __launch_bounds__(256) void k_prep(const float* __restrict__ pts,
                                              const float* __restrict__ prop,
                                              float* __restrict__ xx,
                                              float* __restrict__ xy,
                                              float* __restrict__ xz) {
  int t = blockIdx.x * 256 + threadIdx.x;
  if (t >= N_PTS) return;
  float x = prop[0], y = prop[1];
  xx[t] = __fsub_rn(pts[3 * t + 0], x);
  xy[t] = __fsub_rn(pts[3 * t + 1], y);
  xz[t] = pts[3 * t + 2];
}

// ---------------- spatial sort preprocess (for pruned FPS1) ----------------
// 16^3 Morton cells over [-4.5,4.5)^3. Intra-cell order is nondeterministic
// (atomicAdd) but FPS output is invariant: d-updates are per-point exact and
// the winner is picked by atomicMin over ORIGINAL indices (= jnp.argmax
// first-max semantics) among bitwise-max holders.
__device__ __forceinline__ int spread3(int v) {
  return (v & 1) | ((v & 2) << 2) | ((v & 4) << 4) | ((v & 8) << 6);
}

__global__ __launch_bounds__(256) void k_zerocells(int* __restrict__ cellh) {
  int t = blockIdx.x * 256 + threadIdx.x;
  if (t < NCELL) cellh[t] = 0;
}

__global__ __launch_bounds__(256) void k_cell(const float* __restrict__ xx,
                                              const float* __restrict__ xy,
                                              const float* __restrict__ xz,
                                              int* __restrict__ cellid,
                                              int* __restrict__ cellh) {
  int t = blockIdx.x * 256 + threadIdx.x;
  if (t >= N_PTS) return;
  const float sc = 16.0f / 9.0f;
  int xi = (int)((xx[t] + 4.5f) * sc); xi = xi < 0 ? 0 : (xi > 15 ? 15 : xi);
  int yi = (int)((xy[t] + 4.5f) * sc); yi = yi < 0 ? 0 : (yi > 15 ? 15 : yi);
  int zi = (int)((xz[t] + 4.5f) * sc); zi = zi < 0 ? 0 : (zi > 15 ? 15 : zi);
  int c = spread3(xi) | (spread3(yi) << 1) | (spread3(zi) << 2);
  cellid[t] = c;
  atomicAdd(&cellh[c], 1);
}

// exclusive scan of 4096 ints: 1024 threads x 4 vals, wave shfl scan + LDS
__global__ __launch_bounds__(1024) void k_scan(const int* __restrict__ h,
                                               int* __restrict__ o) {
  __shared__ int wsum[16];
  int tid = threadIdx.x;
  int4 v = *(const int4*)&h[tid * 4];
  int s = v.x + v.y + v.z + v.w;
  int lane = tid & 63;
  int incl = s;
#pragma unroll
  for (int m = 1; m < 64; m <<= 1) {
    int n = __shfl_up(incl, m, 64);
    if (lane >= m) incl += n;
  }
  if (lane == 63) wsum[tid >> 6] = incl;
  __syncthreads();
  int woff = 0;
  for (int w = 0; w < (tid >> 6); ++w) woff += wsum[w];
  int excl = woff + incl - s;
  int4 out;
  out.x = excl;
  out.y = excl + v.x;
  out.z = out.y + v.y;
  out.w = out.z + v.z;
  *(int4*)&o[tid * 4] = out;
}

__global__ __launch_bounds__(256) void k_scatter(const float* __restrict__ xx,
                                                 const float* __restrict__ xy,
                                                 const float* __restrict__ xz,
                                                 const int* __restrict__ cellid,
                                                 int* __restrict__ cello,
                                                 float* __restrict__ spx,
                                                 float* __restrict__ spy,
                                                 float* __restrict__ spz,
                                                 int* __restrict__ perm) {
  int t = blockIdx.x * 256 + threadIdx.x;
  if (t >= N_PTS) return;
  int pos = atomicAdd(&cello[cellid[t]], 1);
  spx[pos] = xx[t];
  spy[pos] = xy[t];
  spz[pos] = xz[t];
  perm[pos] = t;
}

// ---------------- FPS1: 2048 of 32768, single block, bucket-pruned ----------------
// 1024 threads x 32 Morton-consecutive pts/thread. Each thread keeps its bbox;
// per iteration a conservative lower bound on dist^2(centroid, bbox) lets it
// skip the whole 32-pt update when LB*(1-1e-4) >= bmax (then d2 >= d[s] for
// all s, so min() is a no-op: skip is bitwise-exact; margin >> 4-ulp rounding).
// Skip path ~18 VALU ops vs 320. z lives in LDS (128 KB, chunk-XOR swizzled,
// conflict-optimal ds_read_b128); px/py/d in regs(+AGPR). Winner index via
// exec-masked rescan + atomicMin of ORIGINAL indices (perm) into a
// double-buffered slot (2 barriers/iter).
#define F1T 1024
#define F1P 32

__global__
__attribute__((amdgpu_flat_work_group_size(F1T, F1T)))
void k_fps1(const float* __restrict__ xx,
            const float* __restrict__ xy,
            const float* __restrict__ xz,
            const float* __restrict__ spx,
            const float* __restrict__ spy,
            const float* __restrict__ spz,
            const int* __restrict__ perm,
            float* __restrict__ ox,
            float* __restrict__ oy,
            float* __restrict__ oz) {
  __shared__ __align__(16) float zl[F1P * F1T];   // 128 KB, swizzled row-per-thread
  __shared__ float wmax[F1T / 64];                // 16 per-wave maxima
  __shared__ int S[2];                            // double-buffered winner index
  int tid = threadIdx.x;
  char* zb = (char*)zl;
  int rowb = tid * 128 + (tid & 7) * 16;
  int base = tid * F1P;
  float px[F1P], py[F1P], d[F1P];
  float lox = 1e30f, hix = -1e30f, loy = 1e30f, hiy = -1e30f, loz = 1e30f, hiz = -1e30f;
#pragma unroll
  for (int s = 0; s < F1P; ++s) {
    float x = spx[base + s];
    float y = spy[base + s];
    float z = spz[base + s];
    px[s] = x; py[s] = y;
    *(float*)(zb + ((rowb ^ ((s >> 2) * 16)) + (s & 3) * 4)) = z;
    d[s] = 1e10f;
    lox = fminf(lox, x); hix = fmaxf(hix, x);
    loy = fminf(loy, y); hiy = fmaxf(hiy, y);
    loz = fminf(loz, z); hiz = fmaxf(hiz, z);
  }
  float bmax = 1e10f;
  if (tid == 0) { S[0] = 0; S[1] = 0x7fffffff; }
  __syncthreads();
  for (int it = 0; it < NP1; ++it) {
    int f = __builtin_amdgcn_readfirstlane(S[it & 1]);
    float cx = xx[f], cy = xy[f], cz = xz[f];
    if (tid == 0) { ox[it] = cx; oy[it] = cy; oz[it] = cz; }
    // conservative lower bound on squared distance centroid -> thread bbox
    float tx = fmaxf(fmaxf(__fsub_rn(lox, cx), __fsub_rn(cx, hix)), 0.0f);
    float ty = fmaxf(fmaxf(__fsub_rn(loy, cy), __fsub_rn(cy, hiy)), 0.0f);
    float tz = fmaxf(fmaxf(__fsub_rn(loz, cz), __fsub_rn(cz, hiz)), 0.0f);
    float lb = __fadd_rn(__fadd_rn(__fmul_rn(tx, tx), __fmul_rn(ty, ty)), __fmul_rn(tz, tz));
    if (__fmul_rn(lb, 0.9999f) < bmax) {     // else: provably no d[s] changes
      float nb = -1.0f;
#pragma unroll
      for (int c = 0; c < 8; ++c) {
        const float4 zz = *(const float4*)(zb + (rowb ^ (c * 16)));  // ds_read_b128
        float zv[4] = {zz.x, zz.y, zz.z, zz.w};
#pragma unroll
        for (int j = 0; j < 4; ++j) {
          int s = c * 4 + j;
          // exact reference arithmetic: no fma, (dx^2 + dy^2) + dz^2
          float dx = __fsub_rn(px[s], cx);
          float dy = __fsub_rn(py[s], cy);
          float dz = __fsub_rn(zv[j], cz);
          float d2 = __fadd_rn(__fadd_rn(__fmul_rn(dx, dx), __fmul_rn(dy, dy)), __fmul_rn(dz, dz));
          float dn = fminf(d[s], d2);
          d[s] = dn;
          nb = fmaxf(nb, dn);
        }
      }
      bmax = nb;
    }
    float wv = bmax;
#pragma unroll
    for (int m = 1; m < 64; m <<= 1) wv = fmaxf(wv, __shfl_xor(wv, m, 64));
    if ((tid & 63) == 0) wmax[tid >> 6] = wv;
    __syncthreads();                         // (A) wmax ready; all reads of S[it&1] done
    float gb = wmax[tid & 15];               // 16 slots broadcast-read
#pragma unroll
    for (int m = 1; m < 16; m <<= 1) gb = fmaxf(gb, __shfl_xor(gb, m, 64));
    if (bmax == gb) {                        // only threads holding a global max pay the scan
      int cand = 0x7fffffff;
#pragma unroll
      for (int s = 0; s < F1P; ++s)
        if (d[s] == gb) { int oi = perm[base + s]; cand = cand < oi ? cand : oi; }
      atomicMin(&S[(it + 1) & 1], cand);     // smallest ORIGINAL index among max holders
    }
    if (tid == 0) S[it & 1] = 0x7fffffff;    // reset: becomes dst at it+1
    __syncthreads();                         // (B) winner final
  }
}

// ---------------- FPS2: 512 of 2048, single block, 512 threads x 4 pts ----------------
#define F2T 512
#define F2P 4
__global__ __launch_bounds__(F2T, 1) void k_fps2(const float* __restrict__ x1x,
                                                 const float* __restrict__ x1y,
                                                 const float* __restrict__ x1z,
                                                 float* __restrict__ ox,
                                                 float* __restrict__ oy,
                                                 float* __restrict__ oz) {
  __shared__ float sx[NP1], sy[NP1], sz[NP1];   // 24 KB: centroid reads become LDS broadcast
  __shared__ float wmax[F2T / 64];
  __shared__ int S[2];
  int tid = threadIdx.x;
  float px[F2P], py[F2P], pz[F2P], d[F2P];
#pragma unroll
  for (int s = 0; s < F2P; ++s) {
    int i = s * F2T + tid;
    px[s] = x1x[i]; py[s] = x1y[i]; pz[s] = x1z[i];
    sx[i] = px[s];  sy[i] = py[s];  sz[i] = pz[s];
    d[s] = 1e10f;
  }
  if (tid == 0) { S[0] = 0; S[1] = 0x7fffffff; }
  __syncthreads();
  for (int it = 0; it < NP2; ++it) {
    int f = __builtin_amdgcn_readfirstlane(S[it & 1]);
    float cx = sx[f], cy = sy[f], cz = sz[f];  // LDS broadcast
    if (tid == 0) { ox[it] = cx; oy[it] = cy; oz[it] = cz; }
    float bestv = -1.0f;
#pragma unroll
    for (int s = 0; s < F2P; ++s) {
      float dx = __fsub_rn(px[s], cx);
      float dy = __fsub_rn(py[s], cy);
      float dz = __fsub_rn(pz[s], cz);
      float d2 = __fadd_rn(__fadd_rn(__fmul_rn(dx, dx), __fmul_rn(dy, dy)), __fmul_rn(dz, dz));
      float dn = fminf(d[s], d2);
      d[s] = dn;
      bestv = fmaxf(bestv, dn);
    }
    float wv = bestv;
#pragma unroll
    for (int m = 1; m < 64; m <<= 1) wv = fmaxf(wv, __shfl_xor(wv, m, 64));
    if ((tid & 63) == 0) wmax[tid >> 6] = wv;
    __syncthreads();                         // (A)
    float gb = wmax[0];
#pragma unroll
    for (int k = 1; k < F2T / 64; ++k) gb = fmaxf(gb, wmax[k]);
    if (bestv == gb) {
      int cand = 0x7fffffff;
#pragma unroll
      for (int s = F2P - 1; s >= 0; --s) cand = (d[s] == gb) ? (s * F2T + tid) : cand;
      atomicMin(&S[(it + 1) & 1], cand);
    }
    if (tid == 0) S[it & 1] = 0x7fffffff;
    __syncthreads();                         // (B)
  }
}

// ---------------- ball query: first ns indices (ascending) within r2, pad with first ----------------
__global__ void k_ballq(const float* __restrict__ px, const float* __restrict__ py,
                        const float* __restrict__ pz, int n,
                        const float* __restrict__ qx, const float* __restrict__ qy,
                        const float* __restrict__ qz, int S,
                        float r2, int ns, int* __restrict__ out) {
  int w = (blockIdx.x * (int)blockDim.x + threadIdx.x) >> 6;  // one wave per query
  int lane = threadIdx.x & 63;
  if (w >= S) return;
  float cx = qx[w], cy = qy[w], cz = qz[w];
  int found = 0, first = 0;
  bool havefirst = false;
  for (int base = 0; base < n && found < ns; base += 64) {
    int i = base + lane;
    float dx = __fsub_rn(px[i], cx);
    float dy = __fsub_rn(py[i], cy);
    float dz = __fsub_rn(pz[i], cz);
    float d2 = __fadd_rn(__fadd_rn(__fmul_rn(dx, dx), __fmul_rn(dy, dy)), __fmul_rn(dz, dz));
    bool isin = d2 <= r2;
    ull m = __ballot(isin);
    if (!havefirst && m != 0ull) { first = base + __builtin_ctzll(m); havefirst = true; }
    if (isin) {
      int r = (int)__popcll(m & ((1ull << lane) - 1ull));
      int slot = found + r;
      if (slot < ns) out[w * ns + slot] = i;
    }
    found += (int)__popcll(m);
  }
  for (int s2 = found + lane; s2 < ns; s2 += 64) out[w * ns + s2] = first;
}

// ---------------- gather SA1 input rows (15 ch) ----------------
__global__ __launch_bounds__(256) void k_gather1(const float* __restrict__ pts,
                                                 const float* __restrict__ prop,
                                                 const float* __restrict__ xx,
                                                 const float* __restrict__ xy,
                                                 const float* __restrict__ xz,
                                                 const float* __restrict__ x1x,
                                                 const float* __restrict__ x1y,
                                                 const float* __restrict__ x1z,
                                                 const int* __restrict__ gidx,
                                                 float* __restrict__ X, int rbase) {
  int rl = blockIdx.x * 256 + threadIdx.x;
  if (rl >= 8192) return;
  int r = rbase + rl;
  int s = r >> 5;
  int g = gidx[r];
  float x = prop[0], y = prop[1], wz = prop[3];
  float w2 = wz * 0.5f;  // == w/2 exactly
  float oxp = __fadd_rn(x, w2), oxm = __fsub_rn(x, w2);
  float oyp = __fadd_rn(y, w2), oym = __fsub_rn(y, w2);
  float gx = xx[g], gy = xy[g], gz = xz[g];
  float pxv = pts[3 * g + 0], pyv = pts[3 * g + 1];
  float* o = X + (size_t)rl * 15;
  o[0] = __fsub_rn(gx, x1x[s]);
  o[1] = __fsub_rn(gy, x1y[s]);
  o[2] = __fsub_rn(gz, x1z[s]);
  o[3] = __fsub_rn(pxv, oxp);  o[4]  = gy;                    o[5]  = gz;
  o[6] = __fsub_rn(pxv, oxm);  o[7]  = gy;                    o[8]  = gz;
  o[9] = gx;                   o[10] = __fsub_rn(pyv, oyp);   o[11] = gz;
  o[12] = gx;                  o[13] = __fsub_rn(pyv, oym);   o[14] = gz;
}

// ---------------- gather SA2 input rows (131 ch), element-parallel ----------------
__global__ __launch_bounds__(256) void k_gather2(const float* __restrict__ x1x,
                                                 const float* __restrict__ x1y,
                                                 const float* __restrict__ x1z,
                                                 const float* __restrict__ x2x,
                                                 const float* __restrict__ x2y,
                                                 const float* __restrict__ x2z,
                                                 const int* __restrict__ gidx,
                                                 const float* __restrict__ f1,
                                                 float* __restrict__ X, int rbase) {
  int e = blockIdx.x * 256 + threadIdx.x;
  if (e >= 8192 * 131) return;
  int rl = e / 131, c = e % 131;
  int r = rbase + rl;
  int s = r >> 6;
  int g = gidx[r];
  float v;
  if (c == 0)      v = __fsub_rn(x1x[g], x2x[s]);
  else if (c == 1) v = __fsub_rn(x1y[g], x2y[s]);
  else if (c == 2) v = __fsub_rn(x1z[g], x2z[s]);
  else             v = f1[(size_t)g * 128 + (c - 3)];
  X[e] = v;
}

// ---------------- gather SA3 input rows (259 ch) ----------------
__global__ __launch_bounds__(256) void k_gather3(const float* __restrict__ x2x,
                                                 const float* __restrict__ x2y,
                                                 const float* __restrict__ x2z,
                                                 const float* __restrict__ f2,
                                                 float* __restrict__ X) {
  int e = blockIdx.x * 256 + threadIdx.x;
  if (e >= 512 * 259) return;
  int rl = e / 259, c = e % 259;
  float v;
  if (c == 0)      v = x2x[rl];
  else if (c == 1) v = x2y[rl];
  else if (c == 2) v = x2z[rl];
  else             v = f2[(size_t)rl * 256 + (c - 3)];
  X[e] = v;
}

// ---------------- relu GEMM: C[m][n] = relu(bias[n] + sum_k A[m,k]*W[n,k]) ----------------
// 64x64 tile, 256 threads, 4x4 per thread, transposed LDS staging for b128 reads
__global__ __launch_bounds__(256) void k_gemm(const float* __restrict__ A,
                                              const float* __restrict__ W,
                                              const float* __restrict__ bias,
                                              float* __restrict__ C,
                                              int M, int N, int K) {
  __shared__ __align__(16) float As[16][68];
  __shared__ __align__(16) float Bs[16][68];
  int tid = threadIdx.x;
  int bn = blockIdx.x * 64, bm = blockIdx.y * 64;
  int tx = tid & 15, ty = tid >> 4;
  float acc[4][4] = {{0.f, 0.f, 0.f, 0.f}, {0.f, 0.f, 0.f, 0.f},
                     {0.f, 0.f, 0.f, 0.f}, {0.f, 0.f, 0.f, 0.f}};
  for (int k0 = 0; k0 < K; k0 += 16) {
#pragma unroll
    for (int e = 0; e < 4; ++e) {
      int flat = tid + e * 256;
      int rr = flat >> 4, cc = flat & 15;
      As[cc][rr] = (k0 + cc < K) ? A[(size_t)(bm + rr) * K + (k0 + cc)] : 0.0f;
      Bs[cc][rr] = (k0 + cc < K) ? W[(size_t)(bn + rr) * K + (k0 + cc)] : 0.0f;
    }
    __syncthreads();
#pragma unroll
    for (int kk = 0; kk < 16; ++kk) {
      const float4 a = *(const float4*)&As[kk][ty * 4];
      const float4 b = *(const float4*)&Bs[kk][tx * 4];
      float av[4] = {a.x, a.y, a.z, a.w};
      float bb[4] = {b.x, b.y, b.z, b.w};
#pragma unroll
      for (int i = 0; i < 4; ++i)
#pragma unroll
        for (int j = 0; j < 4; ++j)
          acc[i][j] = fmaf(av[i], bb[j], acc[i][j]);
    }
    __syncthreads();
  }
#pragma unroll
  for (int i = 0; i < 4; ++i) {
    int m = bm + ty * 4 + i;
    float4 o;
    o.x = fmaxf(acc[i][0] + bias[bn + tx * 4 + 0], 0.0f);
    o.y = fmaxf(acc[i][1] + bias[bn + tx * 4 + 1], 0.0f);
    o.z = fmaxf(acc[i][2] + bias[bn + tx * 4 + 2], 0.0f);
    o.w = fmaxf(acc[i][3] + bias[bn + tx * 4 + 3], 0.0f);
    *(float4*)&C[(size_t)m * N + bn + tx * 4] = o;
  }
}

// ---------------- maxpool over Ks consecutive rows ----------------
__global__ __launch_bounds__(256) void k_maxpool(const float* __restrict__ H,
                                                 float* __restrict__ F,
                                                 int S, int Ks, int Nch, int sbase) {
  int t = blockIdx.x * 256 + threadIdx.x;
  if (t >= S * Nch) return;
  int sl = t / Nch, n = t % Nch;
  const float* p = H + (size_t)sl * Ks * Nch + n;
  float m = p[0];
  for (int k = 1; k < Ks; ++k) m = fmaxf(m, p[(size_t)k * Nch]);
  F[(size_t)(sbase + sl) * Nch + n] = m;
}

// ---------------- host ----------------
extern "C" void kernel_launch(void* const* d_in, const int* in_sizes, int n_in,
                              void* d_out, int out_size, void* d_ws, size_t ws_size,
                              hipStream_t stream) {
  (void)n_in; (void)out_size; (void)ws_size;
  const float* pts = (const float*)d_in[0];
  const float* prop = (const float*)d_in[1];

  // inputs may arrive in dict order (w0,b0,w1,b1,w2,b2) or signature order (w0,w1,w2,b0,b1,b2)
  bool dict_order = (in_sizes[3] == 64);
  const float *w[3][3], *b[3][3];
  for (int g = 0; g < 3; ++g)
    for (int l = 0; l < 3; ++l) {
      int base = 2 + g * 6;
      int wi = dict_order ? (base + l * 2) : (base + l);
      int bi = dict_order ? (base + l * 2 + 1) : (base + 3 + l);
      w[g][l] = (const float*)d_in[wi];
      b[g][l] = (const float*)d_in[bi];
    }

  float* ws = (float*)d_ws;
  float* xx = ws;
  float* xy = xx + N_PTS;
  float* xz = xy + N_PTS;
  float* x1x = xz + N_PTS;
  float* x1y = x1x + NP1;
  float* x1z = x1y + NP1;
  float* x2x = x1z + NP1;
  float* x2y = x2x + NP2;
  float* x2z = x2y + NP2;
  int* gidx1 = (int*)(x2z + NP2);            // 2048*32
  int* gidx2 = gidx1 + NP1 * NSAMP1;         // 512*64
  float* f1 = (float*)(gidx2 + NP2 * NSAMP2);// 2048*128
  float* f2 = f1 + NP1 * 128;                // 512*256
  float* Xp = f2 + NP2 * 256;                // 8192*131 pool (also 8192*15, 512*259)
  float* Ha = Xp + 8192 * 131;               // 8192*128 pool
  float* Hb = Ha + 8192 * 128;               // 8192*128 pool
  float* Hc = Hb + 8192 * 128;               // 8192*256 pool (also 512*1024)

  // sort scratch carved from the Xp pool (free until k_gather1 runs)
  int*   cellid = (int*)Xp;                  // 32768
  int*   cellh  = cellid + N_PTS;            // 4096
  int*   cello  = cellh + NCELL;             // 4096
  int*   perm   = cello + NCELL;             // 32768
  float* spx    = (float*)(perm + N_PTS);    // 32768
  float* spy    = spx + N_PTS;               // 32768
  float* spz    = spy + N_PTS;               // 32768  (total 172K ints << Xp pool)

  const float R2A = (float)(0.4 * 0.4);  // f32 of python-f64 product: 1 ulp below 0.4f*0.4f
  const float R2B = (float)(0.8 * 0.8);

  k_prep<<<128, 256, 0, stream>>>(pts, prop, xx, xy, xz);
  k_zerocells<<<16, 256, 0, stream>>>(cellh);
  k_cell<<<128, 256, 0, stream>>>(xx, xy, xz, cellid, cellh);
  k_scan<<<1, 1024, 0, stream>>>(cellh, cello);
  k_scatter<<<128, 256, 0, stream>>>(xx, xy, xz, cellid, cello, spx, spy, spz, perm);
  k_fps1<<<1, F1T, 0, stream>>>(xx, xy, xz, spx, spy, spz, perm, x1x, x1y, x1z);
  k_fps2<<<1, F2T, 0, stream>>>(x1x, x1y, x1z, x2x, x2y, x2z);
  k_ballq<<<512, 256, 0, stream>>>(xx, xy, xz, N_PTS, x1x, x1y, x1z, NP1, R2A, NSAMP1, gidx1);
  k_ballq<<<128, 256, 0, stream>>>(x1x, x1y, x1z, NP1, x2x, x2y, x2z, NP2, R2B, NSAMP2, gidx2);

  // SA1: 65536 rows in 8 chunks of 8192 (s-chunks of 256)
  for (int ch = 0; ch < 8; ++ch) {
    int rbase = ch * 8192;
    k_gather1<<<32, 256, 0, stream>>>(pts, prop, xx, xy, xz, x1x, x1y, x1z, gidx1, Xp, rbase);
    k_gemm<<<dim3(1, 128), 256, 0, stream>>>(Xp, w[0][0], b[0][0], Ha, 8192, 64, 15);
    k_gemm<<<dim3(1, 128), 256, 0, stream>>>(Ha, w[0][1], b[0][1], Hb, 8192, 64, 64);
    k_gemm<<<dim3(2, 128), 256, 0, stream>>>(Hb, w[0][2], b[0][2], Hc, 8192, 128, 64);
    k_maxpool<<<128, 256, 0, stream>>>(Hc, f1, 256, 32, 128, ch * 256);
  }

  // SA2: 32768 rows in 4 chunks of 8192 (s-chunks of 128)
  for (int ch = 0; ch < 4; ++ch) {
    int rbase = ch * 8192;
    k_gather2<<<(8192 * 131 + 255) / 256, 256, 0, stream>>>(x1x, x1y, x1z, x2x, x2y, x2z,
                                                            gidx2, f1, Xp, rbase);
    k_gemm<<<dim3(2, 128), 256, 0, stream>>>(Xp, w[1][0], b[1][0], Ha, 8192, 128, 131);
    k_gemm<<<dim3(2, 128), 256, 0, stream>>>(Ha, w[1][1], b[1][1], Hb, 8192, 128, 128);
    k_gemm<<<dim3(4, 128), 256, 0, stream>>>(Hb, w[1][2], b[1][2], Hc, 8192, 256, 128);
    k_maxpool<<<128, 256, 0, stream>>>(Hc, f2, 128, 64, 256, ch * 128);
  }

  // SA3
  k_gather3<<<(512 * 259 + 255) / 256, 256, 0, stream>>>(x2x, x2y, x2z, f2, Xp);
  k_gemm<<<dim3(4, 8), 256, 0, stream>>>(Xp, w[2][0], b[2][0], Ha, 512, 256, 259);
  k_gemm<<<dim3(8, 8), 256, 0, stream>>>(Ha, w[2][1], b[2][1], Hb, 512, 512, 256);
  k_gemm<<<dim3(16, 8), 256, 0, stream>>>(Hb, w[2][2], b[2][2], Hc, 512, 1024, 512);
  k_maxpool<<<4, 256, 0, stream>>>(Hc, (float*)d_out, 1, 512, 1024, 0);
}

// Round 8
// 8763.071 us; speedup vs baseline: 1.0899x; 1.0899x over previous
//
#include <hip/hip_runtime.h>
#include <cstdint>
#include <cstddef>

typedef unsigned long long ull;

#define N_PTS  32768
#define NP1    2048
#define NSAMP1 32
#define NP2    512
#define NSAMP2 64
#define NCELL  4096

// ---------------- prep: xyz = points - [x,y,0], SoA ----------------
__global__ __launch_bounds__(256) void k_prep(const float* __restrict__ pts,
                                              const float* __restrict__ prop,
                                              float* __restrict__ xx,
                                              float* __restrict__ xy,
                                              float* __restrict__ xz) {
  int t = blockIdx.x * 256 + threadIdx.x;
  if (t >= N_PTS) return;
  float x = prop[0], y = prop[1];
  xx[t] = __fsub_rn(pts[3 * t + 0], x);
  xy[t] = __fsub_rn(pts[3 * t + 1], y);
  xz[t] = pts[3 * t + 2];
}

// ---------------- spatial sort preprocess (for pruned FPS1) ----------------
// 16^3 Morton cells over [-4.5,4.5)^3. Intra-cell order is nondeterministic
// (atomicAdd) but FPS output is invariant: d-updates are per-point exact and
// the winner is picked by atomicMin over ORIGINAL indices (= jnp.argmax
// first-max semantics) among bitwise-max holders.
__device__ __forceinline__ int spread3(int v) {
  return (v & 1) | ((v & 2) << 2) | ((v & 4) << 4) | ((v & 8) << 6);
}

__global__ __launch_bounds__(256) void k_zerocells(int* __restrict__ cellh) {
  int t = blockIdx.x * 256 + threadIdx.x;
  if (t < NCELL) cellh[t] = 0;
}

__global__ __launch_bounds__(256) void k_cell(const float* __restrict__ xx,
                                              const float* __restrict__ xy,
                                              const float* __restrict__ xz,
                                              int* __restrict__ cellid,
                                              int* __restrict__ cellh) {
  int t = blockIdx.x * 256 + threadIdx.x;
  if (t >= N_PTS) return;
  const float sc = 16.0f / 9.0f;
  int xi = (int)((xx[t] + 4.5f) * sc); xi = xi < 0 ? 0 : (xi > 15 ? 15 : xi);
  int yi = (int)((xy[t] + 4.5f) * sc); yi = yi < 0 ? 0 : (yi > 15 ? 15 : yi);
  int zi = (int)((xz[t] + 4.5f) * sc); zi = zi < 0 ? 0 : (zi > 15 ? 15 : zi);
  int c = spread3(xi) | (spread3(yi) << 1) | (spread3(zi) << 2);
  cellid[t] = c;
  atomicAdd(&cellh[c], 1);
}

// exclusive scan of 4096 ints: 1024 threads x 4 vals, wave shfl scan + LDS
__global__ __launch_bounds__(1024) void k_scan(const int* __restrict__ h,
                                               int* __restrict__ o) {
  __shared__ int wsum[16];
  int tid = threadIdx.x;
  int4 v = *(const int4*)&h[tid * 4];
  int s = v.x + v.y + v.z + v.w;
  int lane = tid & 63;
  int incl = s;
#pragma unroll
  for (int m = 1; m < 64; m <<= 1) {
    int n = __shfl_up(incl, m, 64);
    if (lane >= m) incl += n;
  }
  if (lane == 63) wsum[tid >> 6] = incl;
  __syncthreads();
  int woff = 0;
  for (int w = 0; w < (tid >> 6); ++w) woff += wsum[w];
  int excl = woff + incl - s;
  int4 out;
  out.x = excl;
  out.y = excl + v.x;
  out.z = out.y + v.y;
  out.w = out.z + v.z;
  *(int4*)&o[tid * 4] = out;
}

__global__ __launch_bounds__(256) void k_scatter(const float* __restrict__ xx,
                                                 const float* __restrict__ xy,
                                                 const float* __restrict__ xz,
                                                 const int* __restrict__ cellid,
                                                 int* __restrict__ cello,
                                                 float* __restrict__ spx,
                                                 float* __restrict__ spy,
                                                 float* __restrict__ spz,
                                                 int* __restrict__ perm) {
  int t = blockIdx.x * 256 + threadIdx.x;
  if (t >= N_PTS) return;
  int pos = atomicAdd(&cello[cellid[t]], 1);
  spx[pos] = xx[t];
  spy[pos] = xy[t];
  spz[pos] = xz[t];
  perm[pos] = t;
}

// ---------------- FPS1: 2048 of 32768, single block, bucket-pruned ----------------
// 1024 threads x 32 Morton-consecutive pts/thread, bbox skip-test per thread
// (R7: pruning confirmed working — per-CU VALUBusy 92%->19% — but duration
// 2x'd because the per-iter centroid loads xx[f]/xy[f]/xz[f] became cold
// HBM misses (~900cyc dependent chain, FETCH +334KB) with no VALU to hide
// them). R8 fix: centroid never touches global — the unique winner-owner
// thread publishes {x,y,z} into an LDS float4 (captured with STATIC indexing
// in the rescan loop; runtime-indexed reg arrays would spill) and writes
// ox[it+1] itself. 3 barriers/iter: A(wmax ready), B(atomicMin final),
// C(coords published). S double-buffered; reset after barrier A is race-free.
#define F1T 1024
#define F1P 32

__global__
__attribute__((amdgpu_flat_work_group_size(F1T, F1T)))
void k_fps1(const float* __restrict__ spx,
            const float* __restrict__ spy,
            const float* __restrict__ spz,
            const int* __restrict__ perm,
            float* __restrict__ ox,
            float* __restrict__ oy,
            float* __restrict__ oz) {
  __shared__ __align__(16) float zl[F1P * F1T];   // 128 KB, swizzled row-per-thread
  __shared__ float wmax[F1T / 64];                // 16 per-wave maxima
  __shared__ float4 C4;                           // current centroid (broadcast)
  __shared__ int S[2];                            // double-buffered winner org-index
  int tid = threadIdx.x;
  char* zb = (char*)zl;
  int rowb = tid * 128 + (tid & 7) * 16;
  int base = tid * F1P;
  float px[F1P], py[F1P], d[F1P];
  float lox = 1e30f, hix = -1e30f, loy = 1e30f, hiy = -1e30f, loz = 1e30f, hiz = -1e30f;
#pragma unroll
  for (int q = 0; q < 8; ++q) {
    float4 vx = *(const float4*)&spx[base + q * 4];
    float4 vy = *(const float4*)&spy[base + q * 4];
    float4 vz = *(const float4*)&spz[base + q * 4];
    int4   vp = *(const int4*)&perm[base + q * 4];
    *(float4*)(zb + (rowb ^ (q * 16))) = vz;      // ds_write_b128, swizzled
    float fx[4] = {vx.x, vx.y, vx.z, vx.w};
    float fy[4] = {vy.x, vy.y, vy.z, vy.w};
    float fz[4] = {vz.x, vz.y, vz.z, vz.w};
    int   ip[4] = {vp.x, vp.y, vp.z, vp.w};
#pragma unroll
    for (int j = 0; j < 4; ++j) {
      int s = q * 4 + j;
      px[s] = fx[j]; py[s] = fy[j]; d[s] = 1e10f;
      lox = fminf(lox, fx[j]); hix = fmaxf(hix, fx[j]);
      loy = fminf(loy, fy[j]); hiy = fmaxf(hiy, fy[j]);
      loz = fminf(loz, fz[j]); hiz = fmaxf(hiz, fz[j]);
      if (ip[j] == 0) {                           // owner of original index 0
        C4 = make_float4(fx[j], fy[j], fz[j], 0.0f);
        ox[0] = fx[j]; oy[0] = fy[j]; oz[0] = fz[j];
      }
    }
  }
  float bmax = 1e10f;
  if (tid == 0) { S[0] = 0x7fffffff; S[1] = 0x7fffffff; }
  __syncthreads();
  for (int it = 0; it < NP1 - 1; ++it) {
    float4 c = C4;                                // one LDS broadcast read
    float cx = c.x, cy = c.y, cz = c.z;
    // conservative lower bound on squared distance centroid -> thread bbox
    float tx = fmaxf(fmaxf(__fsub_rn(lox, cx), __fsub_rn(cx, hix)), 0.0f);
    float ty = fmaxf(fmaxf(__fsub_rn(loy, cy), __fsub_rn(cy, hiy)), 0.0f);
    float tz = fmaxf(fmaxf(__fsub_rn(loz, cz), __fsub_rn(cz, hiz)), 0.0f);
    float lb = __fadd_rn(__fadd_rn(__fmul_rn(tx, tx), __fmul_rn(ty, ty)), __fmul_rn(tz, tz));
    if (__fmul_rn(lb, 0.9999f) < bmax) {          // else: provably no d[s] changes
      float nb = -1.0f;
#pragma unroll
      for (int cch = 0; cch < 8; ++cch) {
        const float4 zz = *(const float4*)(zb + (rowb ^ (cch * 16)));  // ds_read_b128
        float zv[4] = {zz.x, zz.y, zz.z, zz.w};
#pragma unroll
        for (int j = 0; j < 4; ++j) {
          int s = cch * 4 + j;
          // exact reference arithmetic: no fma, (dx^2 + dy^2) + dz^2
          float dx = __fsub_rn(px[s], cx);
          float dy = __fsub_rn(py[s], cy);
          float dz = __fsub_rn(zv[j], cz);
          float d2 = __fadd_rn(__fadd_rn(__fmul_rn(dx, dx), __fmul_rn(dy, dy)), __fmul_rn(dz, dz));
          float dn = fminf(d[s], d2);
          d[s] = dn;
          nb = fmaxf(nb, dn);
        }
      }
      bmax = nb;
    }
    float wv = bmax;
#pragma unroll
    for (int m = 1; m < 64; m <<= 1) wv = fmaxf(wv, __shfl_xor(wv, m, 64));
    if ((tid & 63) == 0) wmax[tid >> 6] = wv;
    __syncthreads();                              // (A) wmax ready
    if (tid == 0) S[(it + 1) & 1] = 0x7fffffff;   // reset other slot (no readers now)
    float gb = wmax[tid & 15];                    // 16 slots broadcast-read
#pragma unroll
    for (int m = 1; m < 16; m <<= 1) gb = fmaxf(gb, __shfl_xor(gb, m, 64));
    int cand = 0x7fffffff;
    float wx = 0.0f, wy = 0.0f, wz2 = 0.0f;
    if (bmax == gb) {                             // only global-max holders scan
#pragma unroll
      for (int s = 0; s < F1P; ++s) {
        if (d[s] == gb) {
          int oi = perm[base + s];
          if (oi < cand) {
            cand = oi;                            // STATIC s: no reg-array spill
            wx = px[s]; wy = py[s];
            wz2 = *(const float*)(zb + ((rowb ^ ((s >> 2) * 16)) + (s & 3) * 4));
          }
        }
      }
      atomicMin(&S[it & 1], cand);                // first-max = smallest org index
    }
    __syncthreads();                              // (B) winner final
    if (cand != 0x7fffffff && cand == S[it & 1]) {
      C4 = make_float4(wx, wy, wz2, 0.0f);        // unique owner publishes coords
      ox[it + 1] = wx; oy[it + 1] = wy; oz[it + 1] = wz2;
    }
    __syncthreads();                              // (C) coords published
  }
}

// ---------------- FPS2: 512 of 2048, single block, 512 threads x 4 pts ----------------
#define F2T 512
#define F2P 4
__global__ __launch_bounds__(F2T, 1) void k_fps2(const float* __restrict__ x1x,
                                                 const float* __restrict__ x1y,
                                                 const float* __restrict__ x1z,
                                                 float* __restrict__ ox,
                                                 float* __restrict__ oy,
                                                 float* __restrict__ oz) {
  __shared__ float sx[NP1], sy[NP1], sz[NP1];   // 24 KB: centroid reads become LDS broadcast
  __shared__ float wmax[F2T / 64];
  __shared__ int S[2];
  int tid = threadIdx.x;
  float px[F2P], py[F2P], pz[F2P], d[F2P];
#pragma unroll
  for (int s = 0; s < F2P; ++s) {
    int i = s * F2T + tid;
    px[s] = x1x[i]; py[s] = x1y[i]; pz[s] = x1z[i];
    sx[i] = px[s];  sy[i] = py[s];  sz[i] = pz[s];
    d[s] = 1e10f;
  }
  if (tid == 0) { S[0] = 0; S[1] = 0x7fffffff; }
  __syncthreads();
  for (int it = 0; it < NP2; ++it) {
    int f = __builtin_amdgcn_readfirstlane(S[it & 1]);
    float cx = sx[f], cy = sy[f], cz = sz[f];  // LDS broadcast
    if (tid == 0) { ox[it] = cx; oy[it] = cy; oz[it] = cz; }
    float bestv = -1.0f;
#pragma unroll
    for (int s = 0; s < F2P; ++s) {
      float dx = __fsub_rn(px[s], cx);
      float dy = __fsub_rn(py[s], cy);
      float dz = __fsub_rn(pz[s], cz);
      float d2 = __fadd_rn(__fadd_rn(__fmul_rn(dx, dx), __fmul_rn(dy, dy)), __fmul_rn(dz, dz));
      float dn = fminf(d[s], d2);
      d[s] = dn;
      bestv = fmaxf(bestv, dn);
    }
    float wv = bestv;
#pragma unroll
    for (int m = 1; m < 64; m <<= 1) wv = fmaxf(wv, __shfl_xor(wv, m, 64));
    if ((tid & 63) == 0) wmax[tid >> 6] = wv;
    __syncthreads();                         // (A)
    float gb = wmax[0];
#pragma unroll
    for (int k = 1; k < F2T / 64; ++k) gb = fmaxf(gb, wmax[k]);
    if (bestv == gb) {
      int cand = 0x7fffffff;
#pragma unroll
      for (int s = F2P - 1; s >= 0; --s) cand = (d[s] == gb) ? (s * F2T + tid) : cand;
      atomicMin(&S[(it + 1) & 1], cand);
    }
    if (tid == 0) S[it & 1] = 0x7fffffff;
    __syncthreads();                         // (B)
  }
}

// ---------------- ball query: first ns indices (ascending) within r2, pad with first ----------------
__global__ void k_ballq(const float* __restrict__ px, const float* __restrict__ py,
                        const float* __restrict__ pz, int n,
                        const float* __restrict__ qx, const float* __restrict__ qy,
                        const float* __restrict__ qz, int S,
                        float r2, int ns, int* __restrict__ out) {
  int w = (blockIdx.x * (int)blockDim.x + threadIdx.x) >> 6;  // one wave per query
  int lane = threadIdx.x & 63;
  if (w >= S) return;
  float cx = qx[w], cy = qy[w], cz = qz[w];
  int found = 0, first = 0;
  bool havefirst = false;
  for (int base = 0; base < n && found < ns; base += 64) {
    int i = base + lane;
    float dx = __fsub_rn(px[i], cx);
    float dy = __fsub_rn(py[i], cy);
    float dz = __fsub_rn(pz[i], cz);
    float d2 = __fadd_rn(__fadd_rn(__fmul_rn(dx, dx), __fmul_rn(dy, dy)), __fmul_rn(dz, dz));
    bool isin = d2 <= r2;
    ull m = __ballot(isin);
    if (!havefirst && m != 0ull) { first = base + __builtin_ctzll(m); havefirst = true; }
    if (isin) {
      int r = (int)__popcll(m & ((1ull << lane) - 1ull));
      int slot = found + r;
      if (slot < ns) out[w * ns + slot] = i;
    }
    found += (int)__popcll(m);
  }
  for (int s2 = found + lane; s2 < ns; s2 += 64) out[w * ns + s2] = first;
}

// ---------------- gather SA1 input rows (15 ch) ----------------
__global__ __launch_bounds__(256) void k_gather1(const float* __restrict__ pts,
                                                 const float* __restrict__ prop,
                                                 const float* __restrict__ xx,
                                                 const float* __restrict__ xy,
                                                 const float* __restrict__ xz,
                                                 const float* __restrict__ x1x,
                                                 const float* __restrict__ x1y,
                                                 const float* __restrict__ x1z,
                                                 const int* __restrict__ gidx,
                                                 float* __restrict__ X, int rbase) {
  int rl = blockIdx.x * 256 + threadIdx.x;
  if (rl >= 8192) return;
  int r = rbase + rl;
  int s = r >> 5;
  int g = gidx[r];
  float x = prop[0], y = prop[1], wz = prop[3];
  float w2 = wz * 0.5f;  // == w/2 exactly
  float oxp = __fadd_rn(x, w2), oxm = __fsub_rn(x, w2);
  float oyp = __fadd_rn(y, w2), oym = __fsub_rn(y, w2);
  float gx = xx[g], gy = xy[g], gz = xz[g];
  float pxv = pts[3 * g + 0], pyv = pts[3 * g + 1];
  float* o = X + (size_t)rl * 15;
  o[0] = __fsub_rn(gx, x1x[s]);
  o[1] = __fsub_rn(gy, x1y[s]);
  o[2] = __fsub_rn(gz, x1z[s]);
  o[3] = __fsub_rn(pxv, oxp);  o[4]  = gy;                    o[5]  = gz;
  o[6] = __fsub_rn(pxv, oxm);  o[7]  = gy;                    o[8]  = gz;
  o[9] = gx;                   o[10] = __fsub_rn(pyv, oyp);   o[11] = gz;
  o[12] = gx;                  o[13] = __fsub_rn(pyv, oym);   o[14] = gz;
}

// ---------------- gather SA2 input rows (131 ch), element-parallel ----------------
__global__ __launch_bounds__(256) void k_gather2(const float* __restrict__ x1x,
                                                 const float* __restrict__ x1y,
                                                 const float* __restrict__ x1z,
                                                 const float* __restrict__ x2x,
                                                 const float* __restrict__ x2y,
                                                 const float* __restrict__ x2z,
                                                 const int* __restrict__ gidx,
                                                 const float* __restrict__ f1,
                                                 float* __restrict__ X, int rbase) {
  int e = blockIdx.x * 256 + threadIdx.x;
  if (e >= 8192 * 131) return;
  int rl = e / 131, c = e % 131;
  int r = rbase + rl;
  int s = r >> 6;
  int g = gidx[r];
  float v;
  if (c == 0)      v = __fsub_rn(x1x[g], x2x[s]);
  else if (c == 1) v = __fsub_rn(x1y[g], x2y[s]);
  else if (c == 2) v = __fsub_rn(x1z[g], x2z[s]);
  else             v = f1[(size_t)g * 128 + (c - 3)];
  X[e] = v;
}

// ---------------- gather SA3 input rows (259 ch) ----------------
__global__ __launch_bounds__(256) void k_gather3(const float* __restrict__ x2x,
                                                 const float* __restrict__ x2y,
                                                 const float* __restrict__ x2z,
                                                 const float* __restrict__ f2,
                                                 float* __restrict__ X) {
  int e = blockIdx.x * 256 + threadIdx.x;
  if (e >= 512 * 259) return;
  int rl = e / 259, c = e % 259;
  float v;
  if (c == 0)      v = x2x[rl];
  else if (c == 1) v = x2y[rl];
  else if (c == 2) v = x2z[rl];
  else             v = f2[(size_t)rl * 256 + (c - 3)];
  X[e] = v;
}

// ---------------- relu GEMM: C[m][n] = relu(bias[n] + sum_k A[m,k]*W[n,k]) ----------------
// 64x64 tile, 256 threads, 4x4 per thread, transposed LDS staging for b128 reads
__global__ __launch_bounds__(256) void k_gemm(const float* __restrict__ A,
                                              const float* __restrict__ W,
                                              const float* __restrict__ bias,
                                              float* __restrict__ C,
                                              int M, int N, int K) {
  __shared__ __align__(16) float As[16][68];
  __shared__ __align__(16) float Bs[16][68];
  int tid = threadIdx.x;
  int bn = blockIdx.x * 64, bm = blockIdx.y * 64;
  int tx = tid & 15, ty = tid >> 4;
  float acc[4][4] = {{0.f, 0.f, 0.f, 0.f}, {0.f, 0.f, 0.f, 0.f},
                     {0.f, 0.f, 0.f, 0.f}, {0.f, 0.f, 0.f, 0.f}};
  for (int k0 = 0; k0 < K; k0 += 16) {
#pragma unroll
    for (int e = 0; e < 4; ++e) {
      int flat = tid + e * 256;
      int rr = flat >> 4, cc = flat & 15;
      As[cc][rr] = (k0 + cc < K) ? A[(size_t)(bm + rr) * K + (k0 + cc)] : 0.0f;
      Bs[cc][rr] = (k0 + cc < K) ? W[(size_t)(bn + rr) * K + (k0 + cc)] : 0.0f;
    }
    __syncthreads();
#pragma unroll
    for (int kk = 0; kk < 16; ++kk) {
      const float4 a = *(const float4*)&As[kk][ty * 4];
      const float4 b = *(const float4*)&Bs[kk][tx * 4];
      float av[4] = {a.x, a.y, a.z, a.w};
      float bb[4] = {b.x, b.y, b.z, b.w};
#pragma unroll
      for (int i = 0; i < 4; ++i)
#pragma unroll
        for (int j = 0; j < 4; ++j)
          acc[i][j] = fmaf(av[i], bb[j], acc[i][j]);
    }
    __syncthreads();
  }
#pragma unroll
  for (int i = 0; i < 4; ++i) {
    int m = bm + ty * 4 + i;
    float4 o;
    o.x = fmaxf(acc[i][0] + bias[bn + tx * 4 + 0], 0.0f);
    o.y = fmaxf(acc[i][1] + bias[bn + tx * 4 + 1], 0.0f);
    o.z = fmaxf(acc[i][2] + bias[bn + tx * 4 + 2], 0.0f);
    o.w = fmaxf(acc[i][3] + bias[bn + tx * 4 + 3], 0.0f);
    *(float4*)&C[(size_t)m * N + bn + tx * 4] = o;
  }
}

// ---------------- maxpool over Ks consecutive rows ----------------
__global__ __launch_bounds__(256) void k_maxpool(const float* __restrict__ H,
                                                 float* __restrict__ F,
                                                 int S, int Ks, int Nch, int sbase) {
  int t = blockIdx.x * 256 + threadIdx.x;
  if (t >= S * Nch) return;
  int sl = t / Nch, n = t % Nch;
  const float* p = H + (size_t)sl * Ks * Nch + n;
  float m = p[0];
  for (int k = 1; k < Ks; ++k) m = fmaxf(m, p[(size_t)k * Nch]);
  F[(size_t)(sbase + sl) * Nch + n] = m;
}

// ---------------- host ----------------
extern "C" void kernel_launch(void* const* d_in, const int* in_sizes, int n_in,
                              void* d_out, int out_size, void* d_ws, size_t ws_size,
                              hipStream_t stream) {
  (void)n_in; (void)out_size; (void)ws_size;
  const float* pts = (const float*)d_in[0];
  const float* prop = (const float*)d_in[1];

  // inputs may arrive in dict order (w0,b0,w1,b1,w2,b2) or signature order (w0,w1,w2,b0,b1,b2)
  bool dict_order = (in_sizes[3] == 64);
  const float *w[3][3], *b[3][3];
  for (int g = 0; g < 3; ++g)
    for (int l = 0; l < 3; ++l) {
      int base = 2 + g * 6;
      int wi = dict_order ? (base + l * 2) : (base + l);
      int bi = dict_order ? (base + l * 2 + 1) : (base + 3 + l);
      w[g][l] = (const float*)d_in[wi];
      b[g][l] = (const float*)d_in[bi];
    }

  float* ws = (float*)d_ws;
  float* xx = ws;
  float* xy = xx + N_PTS;
  float* xz = xy + N_PTS;
  float* x1x = xz + N_PTS;
  float* x1y = x1x + NP1;
  float* x1z = x1y + NP1;
  float* x2x = x1z + NP1;
  float* x2y = x2x + NP2;
  float* x2z = x2y + NP2;
  int* gidx1 = (int*)(x2z + NP2);            // 2048*32
  int* gidx2 = gidx1 + NP1 * NSAMP1;         // 512*64
  float* f1 = (float*)(gidx2 + NP2 * NSAMP2);// 2048*128
  float* f2 = f1 + NP1 * 128;                // 512*256
  float* Xp = f2 + NP2 * 256;                // 8192*131 pool (also 8192*15, 512*259)
  float* Ha = Xp + 8192 * 131;               // 8192*128 pool
  float* Hb = Ha + 8192 * 128;               // 8192*128 pool
  float* Hc = Hb + 8192 * 128;               // 8192*256 pool (also 512*1024)

  // sort scratch carved from the Xp pool (free until k_gather1 runs)
  int*   cellid = (int*)Xp;                  // 32768
  int*   cellh  = cellid + N_PTS;            // 4096
  int*   cello  = cellh + NCELL;             // 4096
  int*   perm   = cello + NCELL;             // 32768
  float* spx    = (float*)(perm + N_PTS);    // 32768
  float* spy    = spx + N_PTS;               // 32768
  float* spz    = spy + N_PTS;               // 32768  (total 172K ints << Xp pool)

  const float R2A = (float)(0.4 * 0.4);  // f32 of python-f64 product: 1 ulp below 0.4f*0.4f
  const float R2B = (float)(0.8 * 0.8);

  k_prep<<<128, 256, 0, stream>>>(pts, prop, xx, xy, xz);
  k_zerocells<<<16, 256, 0, stream>>>(cellh);
  k_cell<<<128, 256, 0, stream>>>(xx, xy, xz, cellid, cellh);
  k_scan<<<1, 1024, 0, stream>>>(cellh, cello);
  k_scatter<<<128, 256, 0, stream>>>(xx, xy, xz, cellid, cello, spx, spy, spz, perm);
  k_fps1<<<1, F1T, 0, stream>>>(spx, spy, spz, perm, x1x, x1y, x1z);
  k_fps2<<<1, F2T, 0, stream>>>(x1x, x1y, x1z, x2x, x2y, x2z);
  k_ballq<<<512, 256, 0, stream>>>(xx, xy, xz, N_PTS, x1x, x1y, x1z, NP1, R2A, NSAMP1, gidx1);
  k_ballq<<<128, 256, 0, stream>>>(x1x, x1y, x1z, NP1, x2x, x2y, x2z, NP2, R2B, NSAMP2, gidx2);

  // SA1: 65536 rows in 8 chunks of 8192 (s-chunks of 256)
  for (int ch = 0; ch < 8; ++ch) {
    int rbase = ch * 8192;
    k_gather1<<<32, 256, 0, stream>>>(pts, prop, xx, xy, xz, x1x, x1y, x1z, gidx1, Xp, rbase);
    k_gemm<<<dim3(1, 128), 256, 0, stream>>>(Xp, w[0][0], b[0][0], Ha, 8192, 64, 15);
    k_gemm<<<dim3(1, 128), 256, 0, stream>>>(Ha, w[0][1], b[0][1], Hb, 8192, 64, 64);
    k_gemm<<<dim3(2, 128), 256, 0, stream>>>(Hb, w[0][2], b[0][2], Hc, 8192, 128, 64);
    k_maxpool<<<128, 256, 0, stream>>>(Hc, f1, 256, 32, 128, ch * 256);
  }

  // SA2: 32768 rows in 4 chunks of 8192 (s-chunks of 128)
  for (int ch = 0; ch < 4; ++ch) {
    int rbase = ch * 8192;
    k_gather2<<<(8192 * 131 + 255) / 256, 256, 0, stream>>>(x1x, x1y, x1z, x2x, x2y, x2z,
                                                            gidx2, f1, Xp, rbase);
    k_gemm<<<dim3(2, 128), 256, 0, stream>>>(Xp, w[1][0], b[1][0], Ha, 8192, 128, 131);
    k_gemm<<<dim3(2, 128), 256, 0, stream>>>(Ha, w[1][1], b[1][1], Hb, 8192, 128, 128);
    k_gemm<<<dim3(4, 128), 256, 0, stream>>>(Hb, w[1][2], b[1][2], Hc, 8192, 256, 128);
    k_maxpool<<<128, 256, 0, stream>>>(Hc, f2, 128, 64, 256, ch * 128);
  }

  // SA3
  k_gather3<<<(512 * 259 + 255) / 256, 256, 0, stream>>>(x2x, x2y, x2z, f2, Xp);
  k_gemm<<<dim3(4, 8), 256, 0, stream>>>(Xp, w[2][0], b[2][0], Ha, 512, 256, 259);
  k_gemm<<<dim3(8, 8), 256, 0, stream>>>(Ha, w[2][1], b[2][1], Hb, 512, 512, 256);
  k_gemm<<<dim3(16, 8), 256, 0, stream>>>(Hb, w[2][2], b[2][2], Hc, 512, 1024, 512);
  k_maxpool<<<4, 256, 0, stream>>>(Hc, (float*)d_out, 1, 512, 1024, 0);
}

// Round 9
// 6897.262 us; speedup vs baseline: 1.3847x; 1.2705x over previous
//
#include <hip/hip_runtime.h>
#include <cstdint>
#include <cstddef>

typedef unsigned long long ull;

#define N_PTS  32768
#define NP1    2048
#define NSAMP1 32
#define NP2    512
#define NSAMP2 64

// ---------------- prep: xyz = points - [x,y,0], SoA ----------------
__global__ __launch_bounds__(256) void k_prep(const float* __restrict__ pts,
                                              const float* __restrict__ prop,
                                              float* __restrict__ xx,
                                              float* __restrict__ xy,
                                              float* __restrict__ xz) {
  int t = blockIdx.x * 256 + threadIdx.x;
  if (t >= N_PTS) return;
  float x = prop[0], y = prop[1];
  xx[t] = __fsub_rn(pts[3 * t + 0], x);
  xy[t] = __fsub_rn(pts[3 * t + 1], y);
  xz[t] = pts[3 * t + 2];
}

// ---------------- FPS1: 2048 of 32768, single persistent block ----------------
// R9: revert to the R4 structure (best measured: 4558us; R5-R8 pruning arc
// peaked at 7710 — branch-guarded updates + extra barrier + masked global
// loads exposed a ~9000cyc/iter latency chain, abandoned). One change vs R4:
// the argmax reduction. R4 spent ~1700cyc/iter on {6-shfl + wmax LDS array +
// barrier + 16-read fmax chain + atomicMin + slot reset + barrier}. Now:
// wave-max holders pack key = (it+1)<<52 | f32bits(d)<<20 | (32767-idx) and
// do ONE 64-bit LDS atomicMax into W. Nonneg-float bits are order-isomorphic
// -> max key = max d; ties -> max invIdx = min original idx (= jnp.argmax
// first-max, exact). Iteration tag (12 bits, it+1<=2048) makes stale keys
// always lose: no reset, no double buffer. Two barriers: (R) all reads of W
// done, (F) winner final. 1024 thr x 32 pts; z in LDS (128KB, chunk-XOR
// swizzle, conflict-free ds_read_b128); px/py/d in regs+AGPR (64-VGPR cap is
// allocator-fixed, ~2 AGPR moves/pt measured R4).
#define F1T 1024
#define F1P 32

__global__
__attribute__((amdgpu_flat_work_group_size(F1T, F1T)))
void k_fps1(const float* __restrict__ xx,
            const float* __restrict__ xy,
            const float* __restrict__ xz,
            float* __restrict__ ox,
            float* __restrict__ oy,
            float* __restrict__ oz) {
  __shared__ __align__(16) float zl[F1P * F1T];   // 128 KB, swizzled row-per-thread
  __shared__ ull W;                               // packed winner key
  int tid = threadIdx.x;
  char* zb = (char*)zl;
  // row base with tid-dependent swizzle folded in (bits 4-6 disjoint from
  // tid*128, so base ^ (c*16) == tid*128 + ((tid&7)^c)*16)
  int rowb = tid * 128 + (tid & 7) * 16;
  float px[F1P], py[F1P], d[F1P];
#pragma unroll
  for (int s = 0; s < F1P; ++s) {
    int i = s * F1T + tid;                        // point-major: coalesced
    px[s] = xx[i];
    py[s] = xy[i];
    float z = xz[i];
    *(float*)(zb + ((rowb ^ ((s >> 2) * 16)) + (s & 3) * 4)) = z;
    d[s] = 1e10f;
  }
  if (tid == 0) W = 32767ull;                     // tag 0, idx 0 (invIdx=32767)
  __syncthreads();
  for (int it = 0; it < NP1; ++it) {
    ull wv_ = W;                                  // winner of prev iter (final)
    int f = __builtin_amdgcn_readfirstlane(32767 - (int)(wv_ & 0x7fffull));
    float cx = xx[f], cy = xy[f], cz = xz[f];     // L2-warm broadcast loads
    if (tid == 0) { ox[it] = cx; oy[it] = cy; oz[it] = cz; }
    __syncthreads();                              // (R) all reads of W done
    float bestv = -1.0f;
#pragma unroll
    for (int c = 0; c < 8; ++c) {
      const float4 zz = *(const float4*)(zb + (rowb ^ (c * 16)));  // ds_read_b128
      float zv[4] = {zz.x, zz.y, zz.z, zz.w};
#pragma unroll
      for (int j = 0; j < 4; ++j) {
        int s = c * 4 + j;
        // exact reference arithmetic: no fma, (dx^2 + dy^2) + dz^2
        float dx = __fsub_rn(px[s], cx);
        float dy = __fsub_rn(py[s], cy);
        float dz = __fsub_rn(zv[j], cz);
        float d2 = __fadd_rn(__fadd_rn(__fmul_rn(dx, dx), __fmul_rn(dy, dy)), __fmul_rn(dz, dz));
        float dn = fminf(d[s], d2);
        d[s] = dn;
        bestv = fmaxf(bestv, dn);
      }
    }
    float wv = bestv;
#pragma unroll
    for (int m = 1; m < 64; m <<= 1) wv = fmaxf(wv, __shfl_xor(wv, m, 64));
    if (bestv == wv) {                            // wave-max holders only (~1/wave)
      int cand = 0x7fffffff;
#pragma unroll
      for (int s = F1P - 1; s >= 0; --s) cand = (d[s] == wv) ? (s * F1T + tid) : cand;
      ull key = ((ull)(it + 1) << 52) | ((ull)__float_as_uint(wv) << 20)
              | (ull)(32767 - cand);
      atomicMax(&W, key);                         // cross-wave resolve in HW
    }
    __syncthreads();                              // (F) winner final
  }
}

// ---------------- FPS2: 512 of 2048, single block, 512 threads x 4 pts ----------------
#define F2T 512
#define F2P 4
__global__ __launch_bounds__(F2T, 1) void k_fps2(const float* __restrict__ x1x,
                                                 const float* __restrict__ x1y,
                                                 const float* __restrict__ x1z,
                                                 float* __restrict__ ox,
                                                 float* __restrict__ oy,
                                                 float* __restrict__ oz) {
  __shared__ float sx[NP1], sy[NP1], sz[NP1];   // 24 KB: centroid reads become LDS broadcast
  __shared__ float wmax[F2T / 64];
  __shared__ int S[2];
  int tid = threadIdx.x;
  float px[F2P], py[F2P], pz[F2P], d[F2P];
#pragma unroll
  for (int s = 0; s < F2P; ++s) {
    int i = s * F2T + tid;
    px[s] = x1x[i]; py[s] = x1y[i]; pz[s] = x1z[i];
    sx[i] = px[s];  sy[i] = py[s];  sz[i] = pz[s];
    d[s] = 1e10f;
  }
  if (tid == 0) { S[0] = 0; S[1] = 0x7fffffff; }
  __syncthreads();
  for (int it = 0; it < NP2; ++it) {
    int f = __builtin_amdgcn_readfirstlane(S[it & 1]);
    float cx = sx[f], cy = sy[f], cz = sz[f];  // LDS broadcast
    if (tid == 0) { ox[it] = cx; oy[it] = cy; oz[it] = cz; }
    float bestv = -1.0f;
#pragma unroll
    for (int s = 0; s < F2P; ++s) {
      float dx = __fsub_rn(px[s], cx);
      float dy = __fsub_rn(py[s], cy);
      float dz = __fsub_rn(pz[s], cz);
      float d2 = __fadd_rn(__fadd_rn(__fmul_rn(dx, dx), __fmul_rn(dy, dy)), __fmul_rn(dz, dz));
      float dn = fminf(d[s], d2);
      d[s] = dn;
      bestv = fmaxf(bestv, dn);
    }
    float wv = bestv;
#pragma unroll
    for (int m = 1; m < 64; m <<= 1) wv = fmaxf(wv, __shfl_xor(wv, m, 64));
    if ((tid & 63) == 0) wmax[tid >> 6] = wv;
    __syncthreads();                         // (A)
    float gb = wmax[0];
#pragma unroll
    for (int k = 1; k < F2T / 64; ++k) gb = fmaxf(gb, wmax[k]);
    if (bestv == gb) {
      int cand = 0x7fffffff;
#pragma unroll
      for (int s = F2P - 1; s >= 0; --s) cand = (d[s] == gb) ? (s * F2T + tid) : cand;
      atomicMin(&S[(it + 1) & 1], cand);
    }
    if (tid == 0) S[it & 1] = 0x7fffffff;
    __syncthreads();                         // (B)
  }
}

// ---------------- ball query: first ns indices (ascending) within r2, pad with first ----------------
__global__ void k_ballq(const float* __restrict__ px, const float* __restrict__ py,
                        const float* __restrict__ pz, int n,
                        const float* __restrict__ qx, const float* __restrict__ qy,
                        const float* __restrict__ qz, int S,
                        float r2, int ns, int* __restrict__ out) {
  int w = (blockIdx.x * (int)blockDim.x + threadIdx.x) >> 6;  // one wave per query
  int lane = threadIdx.x & 63;
  if (w >= S) return;
  float cx = qx[w], cy = qy[w], cz = qz[w];
  int found = 0, first = 0;
  bool havefirst = false;
  for (int base = 0; base < n && found < ns; base += 64) {
    int i = base + lane;
    float dx = __fsub_rn(px[i], cx);
    float dy = __fsub_rn(py[i], cy);
    float dz = __fsub_rn(pz[i], cz);
    float d2 = __fadd_rn(__fadd_rn(__fmul_rn(dx, dx), __fmul_rn(dy, dy)), __fmul_rn(dz, dz));
    bool isin = d2 <= r2;
    ull m = __ballot(isin);
    if (!havefirst && m != 0ull) { first = base + __builtin_ctzll(m); havefirst = true; }
    if (isin) {
      int r = (int)__popcll(m & ((1ull << lane) - 1ull));
      int slot = found + r;
      if (slot < ns) out[w * ns + slot] = i;
    }
    found += (int)__popcll(m);
  }
  for (int s2 = found + lane; s2 < ns; s2 += 64) out[w * ns + s2] = first;
}

// ---------------- gather SA1 input rows (15 ch) ----------------
__global__ __launch_bounds__(256) void k_gather1(const float* __restrict__ pts,
                                                 const float* __restrict__ prop,
                                                 const float* __restrict__ xx,
                                                 const float* __restrict__ xy,
                                                 const float* __restrict__ xz,
                                                 const float* __restrict__ x1x,
                                                 const float* __restrict__ x1y,
                                                 const float* __restrict__ x1z,
                                                 const int* __restrict__ gidx,
                                                 float* __restrict__ X, int rbase) {
  int rl = blockIdx.x * 256 + threadIdx.x;
  if (rl >= 8192) return;
  int r = rbase + rl;
  int s = r >> 5;
  int g = gidx[r];
  float x = prop[0], y = prop[1], wz = prop[3];
  float w2 = wz * 0.5f;  // == w/2 exactly
  float oxp = __fadd_rn(x, w2), oxm = __fsub_rn(x, w2);
  float oyp = __fadd_rn(y, w2), oym = __fsub_rn(y, w2);
  float gx = xx[g], gy = xy[g], gz = xz[g];
  float pxv = pts[3 * g + 0], pyv = pts[3 * g + 1];
  float* o = X + (size_t)rl * 15;
  o[0] = __fsub_rn(gx, x1x[s]);
  o[1] = __fsub_rn(gy, x1y[s]);
  o[2] = __fsub_rn(gz, x1z[s]);
  o[3] = __fsub_rn(pxv, oxp);  o[4]  = gy;                    o[5]  = gz;
  o[6] = __fsub_rn(pxv, oxm);  o[7]  = gy;                    o[8]  = gz;
  o[9] = gx;                   o[10] = __fsub_rn(pyv, oyp);   o[11] = gz;
  o[12] = gx;                  o[13] = __fsub_rn(pyv, oym);   o[14] = gz;
}

// ---------------- gather SA2 input rows (131 ch), element-parallel ----------------
__global__ __launch_bounds__(256) void k_gather2(const float* __restrict__ x1x,
                                                 const float* __restrict__ x1y,
                                                 const float* __restrict__ x1z,
                                                 const float* __restrict__ x2x,
                                                 const float* __restrict__ x2y,
                                                 const float* __restrict__ x2z,
                                                 const int* __restrict__ gidx,
                                                 const float* __restrict__ f1,
                                                 float* __restrict__ X, int rbase) {
  int e = blockIdx.x * 256 + threadIdx.x;
  if (e >= 8192 * 131) return;
  int rl = e / 131, c = e % 131;
  int r = rbase + rl;
  int s = r >> 6;
  int g = gidx[r];
  float v;
  if (c == 0)      v = __fsub_rn(x1x[g], x2x[s]);
  else if (c == 1) v = __fsub_rn(x1y[g], x2y[s]);
  else if (c == 2) v = __fsub_rn(x1z[g], x2z[s]);
  else             v = f1[(size_t)g * 128 + (c - 3)];
  X[e] = v;
}

// ---------------- gather SA3 input rows (259 ch) ----------------
__global__ __launch_bounds__(256) void k_gather3(const float* __restrict__ x2x,
                                                 const float* __restrict__ x2y,
                                                 const float* __restrict__ x2z,
                                                 const float* __restrict__ f2,
                                                 float* __restrict__ X) {
  int e = blockIdx.x * 256 + threadIdx.x;
  if (e >= 512 * 259) return;
  int rl = e / 259, c = e % 259;
  float v;
  if (c == 0)      v = x2x[rl];
  else if (c == 1) v = x2y[rl];
  else if (c == 2) v = x2z[rl];
  else             v = f2[(size_t)rl * 256 + (c - 3)];
  X[e] = v;
}

// ---------------- relu GEMM: C[m][n] = relu(bias[n] + sum_k A[m,k]*W[n,k]) ----------------
// 64x64 tile, 256 threads, 4x4 per thread, transposed LDS staging for b128 reads
__global__ __launch_bounds__(256) void k_gemm(const float* __restrict__ A,
                                              const float* __restrict__ W,
                                              const float* __restrict__ bias,
                                              float* __restrict__ C,
                                              int M, int N, int K) {
  __shared__ __align__(16) float As[16][68];
  __shared__ __align__(16) float Bs[16][68];
  int tid = threadIdx.x;
  int bn = blockIdx.x * 64, bm = blockIdx.y * 64;
  int tx = tid & 15, ty = tid >> 4;
  float acc[4][4] = {{0.f, 0.f, 0.f, 0.f}, {0.f, 0.f, 0.f, 0.f},
                     {0.f, 0.f, 0.f, 0.f}, {0.f, 0.f, 0.f, 0.f}};
  for (int k0 = 0; k0 < K; k0 += 16) {
#pragma unroll
    for (int e = 0; e < 4; ++e) {
      int flat = tid + e * 256;
      int rr = flat >> 4, cc = flat & 15;
      As[cc][rr] = (k0 + cc < K) ? A[(size_t)(bm + rr) * K + (k0 + cc)] : 0.0f;
      Bs[cc][rr] = (k0 + cc < K) ? W[(size_t)(bn + rr) * K + (k0 + cc)] : 0.0f;
    }
    __syncthreads();
#pragma unroll
    for (int kk = 0; kk < 16; ++kk) {
      const float4 a = *(const float4*)&As[kk][ty * 4];
      const float4 b = *(const float4*)&Bs[kk][tx * 4];
      float av[4] = {a.x, a.y, a.z, a.w};
      float bb[4] = {b.x, b.y, b.z, b.w};
#pragma unroll
      for (int i = 0; i < 4; ++i)
#pragma unroll
        for (int j = 0; j < 4; ++j)
          acc[i][j] = fmaf(av[i], bb[j], acc[i][j]);
    }
    __syncthreads();
  }
#pragma unroll
  for (int i = 0; i < 4; ++i) {
    int m = bm + ty * 4 + i;
    float4 o;
    o.x = fmaxf(acc[i][0] + bias[bn + tx * 4 + 0], 0.0f);
    o.y = fmaxf(acc[i][1] + bias[bn + tx * 4 + 1], 0.0f);
    o.z = fmaxf(acc[i][2] + bias[bn + tx * 4 + 2], 0.0f);
    o.w = fmaxf(acc[i][3] + bias[bn + tx * 4 + 3], 0.0f);
    *(float4*)&C[(size_t)m * N + bn + tx * 4] = o;
  }
}

// ---------------- maxpool over Ks consecutive rows ----------------
__global__ __launch_bounds__(256) void k_maxpool(const float* __restrict__ H,
                                                 float* __restrict__ F,
                                                 int S, int Ks, int Nch, int sbase) {
  int t = blockIdx.x * 256 + threadIdx.x;
  if (t >= S * Nch) return;
  int sl = t / Nch, n = t % Nch;
  const float* p = H + (size_t)sl * Ks * Nch + n;
  float m = p[0];
  for (int k = 1; k < Ks; ++k) m = fmaxf(m, p[(size_t)k * Nch]);
  F[(size_t)(sbase + sl) * Nch + n] = m;
}

// ---------------- host ----------------
extern "C" void kernel_launch(void* const* d_in, const int* in_sizes, int n_in,
                              void* d_out, int out_size, void* d_ws, size_t ws_size,
                              hipStream_t stream) {
  (void)n_in; (void)out_size; (void)ws_size;
  const float* pts = (const float*)d_in[0];
  const float* prop = (const float*)d_in[1];

  // inputs may arrive in dict order (w0,b0,w1,b1,w2,b2) or signature order (w0,w1,w2,b0,b1,b2)
  bool dict_order = (in_sizes[3] == 64);
  const float *w[3][3], *b[3][3];
  for (int g = 0; g < 3; ++g)
    for (int l = 0; l < 3; ++l) {
      int base = 2 + g * 6;
      int wi = dict_order ? (base + l * 2) : (base + l);
      int bi = dict_order ? (base + l * 2 + 1) : (base + 3 + l);
      w[g][l] = (const float*)d_in[wi];
      b[g][l] = (const float*)d_in[bi];
    }

  float* ws = (float*)d_ws;
  float* xx = ws;
  float* xy = xx + N_PTS;
  float* xz = xy + N_PTS;
  float* x1x = xz + N_PTS;
  float* x1y = x1x + NP1;
  float* x1z = x1y + NP1;
  float* x2x = x1z + NP1;
  float* x2y = x2x + NP2;
  float* x2z = x2y + NP2;
  int* gidx1 = (int*)(x2z + NP2);            // 2048*32
  int* gidx2 = gidx1 + NP1 * NSAMP1;         // 512*64
  float* f1 = (float*)(gidx2 + NP2 * NSAMP2);// 2048*128
  float* f2 = f1 + NP1 * 128;                // 512*256
  float* Xp = f2 + NP2 * 256;                // 8192*131 pool (also 8192*15, 512*259)
  float* Ha = Xp + 8192 * 131;               // 8192*128 pool
  float* Hb = Ha + 8192 * 128;               // 8192*128 pool
  float* Hc = Hb + 8192 * 128;               // 8192*256 pool (also 512*1024)

  const float R2A = (float)(0.4 * 0.4);  // f32 of python-f64 product: 1 ulp below 0.4f*0.4f
  const float R2B = (float)(0.8 * 0.8);

  k_prep<<<128, 256, 0, stream>>>(pts, prop, xx, xy, xz);
  k_fps1<<<1, F1T, 0, stream>>>(xx, xy, xz, x1x, x1y, x1z);
  k_fps2<<<1, F2T, 0, stream>>>(x1x, x1y, x1z, x2x, x2y, x2z);
  k_ballq<<<512, 256, 0, stream>>>(xx, xy, xz, N_PTS, x1x, x1y, x1z, NP1, R2A, NSAMP1, gidx1);
  k_ballq<<<128, 256, 0, stream>>>(x1x, x1y, x1z, NP1, x2x, x2y, x2z, NP2, R2B, NSAMP2, gidx2);

  // SA1: 65536 rows in 8 chunks of 8192 (s-chunks of 256)
  for (int ch = 0; ch < 8; ++ch) {
    int rbase = ch * 8192;
    k_gather1<<<32, 256, 0, stream>>>(pts, prop, xx, xy, xz, x1x, x1y, x1z, gidx1, Xp, rbase);
    k_gemm<<<dim3(1, 128), 256, 0, stream>>>(Xp, w[0][0], b[0][0], Ha, 8192, 64, 15);
    k_gemm<<<dim3(1, 128), 256, 0, stream>>>(Ha, w[0][1], b[0][1], Hb, 8192, 64, 64);
    k_gemm<<<dim3(2, 128), 256, 0, stream>>>(Hb, w[0][2], b[0][2], Hc, 8192, 128, 64);
    k_maxpool<<<128, 256, 0, stream>>>(Hc, f1, 256, 32, 128, ch * 256);
  }

  // SA2: 32768 rows in 4 chunks of 8192 (s-chunks of 128)
  for (int ch = 0; ch < 4; ++ch) {
    int rbase = ch * 8192;
    k_gather2<<<(8192 * 131 + 255) / 256, 256, 0, stream>>>(x1x, x1y, x1z, x2x, x2y, x2z,
                                                            gidx2, f1, Xp, rbase);
    k_gemm<<<dim3(2, 128), 256, 0, stream>>>(Xp, w[1][0], b[1][0], Ha, 8192, 128, 131);
    k_gemm<<<dim3(2, 128), 256, 0, stream>>>(Ha, w[1][1], b[1][1], Hb, 8192, 128, 128);
    k_gemm<<<dim3(4, 128), 256, 0, stream>>>(Hb, w[1][2], b[1][2], Hc, 8192, 256, 128);
    k_maxpool<<<128, 256, 0, stream>>>(Hc, f2, 128, 64, 256, ch * 128);
  }

  // SA3
  k_gather3<<<(512 * 259 + 255) / 256, 256, 0, stream>>>(x2x, x2y, x2z, f2, Xp);
  k_gemm<<<dim3(4, 8), 256, 0, stream>>>(Xp, w[2][0], b[2][0], Ha, 512, 256, 259);
  k_gemm<<<dim3(8, 8), 256, 0, stream>>>(Ha, w[2][1], b[2][1], Hb, 512, 512, 256);
  k_gemm<<<dim3(16, 8), 256, 0, stream>>>(Hb, w[2][2], b[2][2], Hc, 512, 1024, 512);
  k_maxpool<<<4, 256, 0, stream>>>(Hc, (float*)d_out, 1, 512, 1024, 0);
}

// Round 11
// 5992.551 us; speedup vs baseline: 1.5938x; 1.1510x over previous
//
#include <hip/hip_runtime.h>
#include <cstdint>
#include <cstddef>

typedef unsigned long long ull;

#define N_PTS  32768
#define NP1    2048
#define NSAMP1 32
#define NP2    512
#define NSAMP2 64

// ---------------- prep: xyz = points - [x,y,0], SoA; zero fps1 comm slots ----------------
__global__ __launch_bounds__(256) void k_prep(const float* __restrict__ pts,
                                              const float* __restrict__ prop,
                                              float* __restrict__ xx,
                                              float* __restrict__ xy,
                                              float* __restrict__ xz,
                                              ull* __restrict__ slots) {
  int t = blockIdx.x * 256 + threadIdx.x;
  if (blockIdx.x == 0 && threadIdx.x < 64) slots[threadIdx.x] = 0ull;  // 2 bufs x 8 blk x 4 words
  if (t >= N_PTS) return;
  float x = prop[0], y = prop[1];
  xx[t] = __fsub_rn(pts[3 * t + 0], x);
  xy[t] = __fsub_rn(pts[3 * t + 1], y);
  xz[t] = pts[3 * t + 2];
}

// ---------------- FPS1: 2048 of 32768, EIGHT blocks + tagged-slot exchange ----------------
// R10/R11: single-block fps1 is pinned at ~5300cyc/iter (R4 best 4558us;
// 3584cyc VALU = 1 CU doing all 32768 pts + ~1700 serial; R5-R9 micro-variants
// all failed). Go wide: 8 blocks x 1024 thr x 4 pts/thr -> update 640cyc/CU/
// iter, 16 floats state (fits 64-VGPR cap, NO AGPR moves). Cross-block argmax
// via global u64 slots[2][8][4]: word0 = tag(12)<<52|dbits(32)<<20|invidx(15),
// words1-3 = tag|coord-bits. Each word self-tagged -> no fences; buffers
// double-buffered by iter parity -> lap-proof (a block writes tag T+2 to a
// buffer only after every block READ tag T: its iter-T poll saw T+1 from all,
// and writing T+1 required their iter-(T-1) poll consuming T); tags monotonic
// -> no resets (k_prep re-zeroes each launch, graph-replay safe). Wave 0 of
// each block: writes its block-winner words (RELEASE/AGENT, cross-XCD safe),
// polls all 32 words (1 lane each, parallel; divergent spin has no barrier ->
// no deadlock), u64-max -> winner, coords via shfl, LDS broadcast. Ties: max
// invidx = smallest original index = jnp.argmax exact. 8 blocks on an idle
// 256-CU GPU are trivially co-resident (no coop launch needed).
#define F1B 8
#define F1T 1024
#define F1P 4
#define F1OWN (F1T * F1P)   // 4096 pts per block

__global__
__attribute__((amdgpu_flat_work_group_size(F1T, F1T)))
void k_fps1(const float* __restrict__ xx,
            const float* __restrict__ xy,
            const float* __restrict__ xz,
            ull* __restrict__ slots,
            float* __restrict__ ox,
            float* __restrict__ oy,
            float* __restrict__ oz) {
  __shared__ float sx[F1OWN], sy[F1OWN], sz[F1OWN];  // 48 KB winner-coord lookup
  __shared__ ull wk[F1T / 64];                       // 16 per-wave keys
  __shared__ float4 BC;                              // winner broadcast
  int tid = threadIdx.x;
  int b = blockIdx.x;
  int base = b * F1OWN;
  float px[F1P], py[F1P], pz[F1P], d[F1P];
#pragma unroll
  for (int s = 0; s < F1P; ++s) {
    int li = s * F1T + tid;                          // coalesced
    int gi = base + li;
    px[s] = xx[gi]; py[s] = xy[gi]; pz[s] = xz[gi];
    sx[li] = px[s]; sy[li] = py[s]; sz[li] = pz[s];
    d[s] = 1e10f;
  }
  float cx = xx[0], cy = xy[0], cz = xz[0];          // initial centroid = orig idx 0
  if (b == 0 && tid == 0) { ox[0] = cx; oy[0] = cy; oz[0] = cz; }
  __syncthreads();
  int lane = tid & 63, wid = tid >> 6;
  for (int it = 0; it < NP1 - 1; ++it) {
    float bestv = -1.0f;
#pragma unroll
    for (int s = 0; s < F1P; ++s) {
      // exact reference arithmetic: no fma, (dx^2 + dy^2) + dz^2
      float dx = __fsub_rn(px[s], cx);
      float dy = __fsub_rn(py[s], cy);
      float dz = __fsub_rn(pz[s], cz);
      float d2 = __fadd_rn(__fadd_rn(__fmul_rn(dx, dx), __fmul_rn(dy, dy)), __fmul_rn(dz, dz));
      float dn = fminf(d[s], d2);
      d[s] = dn;
      bestv = fmaxf(bestv, dn);
    }
    int cand = 0;
#pragma unroll
    for (int s = F1P - 1; s >= 0; --s) cand = (d[s] == bestv) ? (base + s * F1T + tid) : cand;
    ull key = ((ull)__float_as_uint(bestv) << 20) | (ull)(32767 - cand);
#pragma unroll
    for (int m = 1; m < 64; m <<= 1) { ull o = __shfl_xor(key, m, 64); key = o > key ? o : key; }
    if (lane == 0) wk[wid] = key;
    __syncthreads();                                 // bar1: wk ready
    if (wid == 0) {
      ull k2 = (lane < F1T / 64) ? wk[lane] : 0ull;
#pragma unroll
      for (int m = 1; m < 16; m <<= 1) { ull o = __shfl_xor(k2, m, 64); k2 = o > k2 ? o : k2; }
      ull tag = (ull)(it + 1) << 52;
      ull* sb = slots + (size_t)((it + 1) & 1) * (F1B * 4);
      int liw = (32767 - (int)(k2 & 0x7fffull)) - base;    // block-winner local idx
      if (lane < 4) {
        ull word;
        if      (lane == 0) word = tag | k2;
        else if (lane == 1) word = tag | (ull)__float_as_uint(sx[liw]);
        else if (lane == 2) word = tag | (ull)__float_as_uint(sy[liw]);
        else                word = tag | (ull)__float_as_uint(sz[liw]);
        __hip_atomic_store(&sb[b * 4 + lane], word, __ATOMIC_RELEASE, __HIP_MEMORY_SCOPE_AGENT);
      }
      ull w = 0;
      if (lane < F1B * 4) {                          // lane -> (block L/4, word L%4)
        do {
          w = __hip_atomic_load(&sb[lane], __ATOMIC_ACQUIRE, __HIP_MEMORY_SCOPE_AGENT);
        } while ((w >> 52) != (ull)(it + 1));
      }
      ull a = ((lane & 3) == 0 && lane < F1B * 4) ? w : 0ull;
#pragma unroll
      for (int m = 4; m < 32; m <<= 1) { ull o = __shfl_xor(a, m, 64); a = o > a ? o : a; }
      ull a0 = __shfl(a, 0, 64);
      int iw = 32767 - (int)(a0 & 0x7fffull);        // global winner original idx
      int wb = iw >> 12;                             // 4096 pts/block
      ull xw = __shfl(w, wb * 4 + 1, 64);
      ull yw = __shfl(w, wb * 4 + 2, 64);
      ull zw = __shfl(w, wb * 4 + 3, 64);
      if (lane == 0) {
        float wx = __uint_as_float((unsigned)xw);
        float wy = __uint_as_float((unsigned)yw);
        float wz = __uint_as_float((unsigned)zw);
        BC = make_float4(wx, wy, wz, 0.0f);
        if (b == 0) { ox[it + 1] = wx; oy[it + 1] = wy; oz[it + 1] = wz; }
      }
    }
    __syncthreads();                                 // bar2: BC published
    float4 c = BC;
    cx = c.x; cy = c.y; cz = c.z;
  }
}

// ---------------- FPS2: 512 of 2048, single block, 512 threads x 4 pts ----------------
#define F2T 512
#define F2P 4
__global__ __launch_bounds__(F2T, 1) void k_fps2(const float* __restrict__ x1x,
                                                 const float* __restrict__ x1y,
                                                 const float* __restrict__ x1z,
                                                 float* __restrict__ ox,
                                                 float* __restrict__ oy,
                                                 float* __restrict__ oz) {
  __shared__ float sx[NP1], sy[NP1], sz[NP1];   // 24 KB: centroid reads become LDS broadcast
  __shared__ float wmax[F2T / 64];
  __shared__ int S[2];
  int tid = threadIdx.x;
  float px[F2P], py[F2P], pz[F2P], d[F2P];
#pragma unroll
  for (int s = 0; s < F2P; ++s) {
    int i = s * F2T + tid;
    px[s] = x1x[i]; py[s] = x1y[i]; pz[s] = x1z[i];
    sx[i] = px[s];  sy[i] = py[s];  sz[i] = pz[s];
    d[s] = 1e10f;
  }
  if (tid == 0) { S[0] = 0; S[1] = 0x7fffffff; }
  __syncthreads();
  for (int it = 0; it < NP2; ++it) {
    int f = __builtin_amdgcn_readfirstlane(S[it & 1]);
    float cx = sx[f], cy = sy[f], cz = sz[f];  // LDS broadcast
    if (tid == 0) { ox[it] = cx; oy[it] = cy; oz[it] = cz; }
    float bestv = -1.0f;
#pragma unroll
    for (int s = 0; s < F2P; ++s) {
      float dx = __fsub_rn(px[s], cx);
      float dy = __fsub_rn(py[s], cy);
      float dz = __fsub_rn(pz[s], cz);
      float d2 = __fadd_rn(__fadd_rn(__fmul_rn(dx, dx), __fmul_rn(dy, dy)), __fmul_rn(dz, dz));
      float dn = fminf(d[s], d2);
      d[s] = dn;
      bestv = fmaxf(bestv, dn);
    }
    float wv = bestv;
#pragma unroll
    for (int m = 1; m < 64; m <<= 1) wv = fmaxf(wv, __shfl_xor(wv, m, 64));
    if ((tid & 63) == 0) wmax[tid >> 6] = wv;
    __syncthreads();                         // (A)
    float gb = wmax[0];
#pragma unroll
    for (int k = 1; k < F2T / 64; ++k) gb = fmaxf(gb, wmax[k]);
    if (bestv == gb) {
      int cand = 0x7fffffff;
#pragma unroll
      for (int s = F2P - 1; s >= 0; --s) cand = (d[s] == gb) ? (s * F2T + tid) : cand;
      atomicMin(&S[(it + 1) & 1], cand);
    }
    if (tid == 0) S[it & 1] = 0x7fffffff;
    __syncthreads();                         // (B)
  }
}

// ---------------- ball query: first ns indices (ascending) within r2, pad with first ----------------
__global__ void k_ballq(const float* __restrict__ px, const float* __restrict__ py,
                        const float* __restrict__ pz, int n,
                        const float* __restrict__ qx, const float* __restrict__ qy,
                        const float* __restrict__ qz, int S,
                        float r2, int ns, int* __restrict__ out) {
  int w = (blockIdx.x * (int)blockDim.x + threadIdx.x) >> 6;  // one wave per query
  int lane = threadIdx.x & 63;
  if (w >= S) return;
  float cx = qx[w], cy = qy[w], cz = qz[w];
  int found = 0, first = 0;
  bool havefirst = false;
  for (int base = 0; base < n && found < ns; base += 64) {
    int i = base + lane;
    float dx = __fsub_rn(px[i], cx);
    float dy = __fsub_rn(py[i], cy);
    float dz = __fsub_rn(pz[i], cz);
    float d2 = __fadd_rn(__fadd_rn(__fmul_rn(dx, dx), __fmul_rn(dy, dy)), __fmul_rn(dz, dz));
    bool isin = d2 <= r2;
    ull m = __ballot(isin);
    if (!havefirst && m != 0ull) { first = base + __builtin_ctzll(m); havefirst = true; }
    if (isin) {
      int r = (int)__popcll(m & ((1ull << lane) - 1ull));
      int slot = found + r;
      if (slot < ns) out[w * ns + slot] = i;
    }
    found += (int)__popcll(m);
  }
  for (int s2 = found + lane; s2 < ns; s2 += 64) out[w * ns + s2] = first;
}

// ---------------- gather SA1 input rows (15 ch) ----------------
__global__ __launch_bounds__(256) void k_gather1(const float* __restrict__ pts,
                                                 const float* __restrict__ prop,
                                                 const float* __restrict__ xx,
                                                 const float* __restrict__ xy,
                                                 const float* __restrict__ xz,
                                                 const float* __restrict__ x1x,
                                                 const float* __restrict__ x1y,
                                                 const float* __restrict__ x1z,
                                                 const int* __restrict__ gidx,
                                                 float* __restrict__ X, int rbase) {
  int rl = blockIdx.x * 256 + threadIdx.x;
  if (rl >= 8192) return;
  int r = rbase + rl;
  int s = r >> 5;
  int g = gidx[r];
  float x = prop[0], y = prop[1], wz = prop[3];
  float w2 = wz * 0.5f;  // == w/2 exactly
  float oxp = __fadd_rn(x, w2), oxm = __fsub_rn(x, w2);
  float oyp = __fadd_rn(y, w2), oym = __fsub_rn(y, w2);
  float gx = xx[g], gy = xy[g], gz = xz[g];
  float pxv = pts[3 * g + 0], pyv = pts[3 * g + 1];
  float* o = X + (size_t)rl * 15;
  o[0] = __fsub_rn(gx, x1x[s]);
  o[1] = __fsub_rn(gy, x1y[s]);
  o[2] = __fsub_rn(gz, x1z[s]);
  o[3] = __fsub_rn(pxv, oxp);  o[4]  = gy;                    o[5]  = gz;
  o[6] = __fsub_rn(pxv, oxm);  o[7]  = gy;                    o[8]  = gz;
  o[9] = gx;                   o[10] = __fsub_rn(pyv, oyp);   o[11] = gz;
  o[12] = gx;                  o[13] = __fsub_rn(pyv, oym);   o[14] = gz;
}

// ---------------- gather SA2 input rows (131 ch), element-parallel ----------------
__global__ __launch_bounds__(256) void k_gather2(const float* __restrict__ x1x,
                                                 const float* __restrict__ x1y,
                                                 const float* __restrict__ x1z,
                                                 const float* __restrict__ x2x,
                                                 const float* __restrict__ x2y,
                                                 const float* __restrict__ x2z,
                                                 const int* __restrict__ gidx,
                                                 const float* __restrict__ f1,
                                                 float* __restrict__ X, int rbase) {
  int e = blockIdx.x * 256 + threadIdx.x;
  if (e >= 8192 * 131) return;
  int rl = e / 131, c = e % 131;
  int r = rbase + rl;
  int s = r >> 6;
  int g = gidx[r];
  float v;
  if (c == 0)      v = __fsub_rn(x1x[g], x2x[s]);
  else if (c == 1) v = __fsub_rn(x1y[g], x2y[s]);
  else if (c == 2) v = __fsub_rn(x1z[g], x2z[s]);
  else             v = f1[(size_t)g * 128 + (c - 3)];
  X[e] = v;
}

// ---------------- gather SA3 input rows (259 ch) ----------------
__global__ __launch_bounds__(256) void k_gather3(const float* __restrict__ x2x,
                                                 const float* __restrict__ x2y,
                                                 const float* __restrict__ x2z,
                                                 const float* __restrict__ f2,
                                                 float* __restrict__ X) {
  int e = blockIdx.x * 256 + threadIdx.x;
  if (e >= 512 * 259) return;
  int rl = e / 259, c = e % 259;
  float v;
  if (c == 0)      v = x2x[rl];
  else if (c == 1) v = x2y[rl];
  else if (c == 2) v = x2z[rl];
  else             v = f2[(size_t)rl * 256 + (c - 3)];
  X[e] = v;
}

// ---------------- relu GEMM: C[m][n] = relu(bias[n] + sum_k A[m,k]*W[n,k]) ----------------
// 64x64 tile, 256 threads, 4x4 per thread, transposed LDS staging for b128 reads
__global__ __launch_bounds__(256) void k_gemm(const float* __restrict__ A,
                                              const float* __restrict__ W,
                                              const float* __restrict__ bias,
                                              float* __restrict__ C,
                                              int M, int N, int K) {
  __shared__ __align__(16) float As[16][68];
  __shared__ __align__(16) float Bs[16][68];
  int tid = threadIdx.x;
  int bn = blockIdx.x * 64, bm = blockIdx.y * 64;
  int tx = tid & 15, ty = tid >> 4;
  float acc[4][4] = {{0.f, 0.f, 0.f, 0.f}, {0.f, 0.f, 0.f, 0.f},
                     {0.f, 0.f, 0.f, 0.f}, {0.f, 0.f, 0.f, 0.f}};
  for (int k0 = 0; k0 < K; k0 += 16) {
#pragma unroll
    for (int e = 0; e < 4; ++e) {
      int flat = tid + e * 256;
      int rr = flat >> 4, cc = flat & 15;
      As[cc][rr] = (k0 + cc < K) ? A[(size_t)(bm + rr) * K + (k0 + cc)] : 0.0f;
      Bs[cc][rr] = (k0 + cc < K) ? W[(size_t)(bn + rr) * K + (k0 + cc)] : 0.0f;
    }
    __syncthreads();
#pragma unroll
    for (int kk = 0; kk < 16; ++kk) {
      const float4 a = *(const float4*)&As[kk][ty * 4];
      const float4 b = *(const float4*)&Bs[kk][tx * 4];
      float av[4] = {a.x, a.y, a.z, a.w};
      float bb[4] = {b.x, b.y, b.z, b.w};
#pragma unroll
      for (int i = 0; i < 4; ++i)
#pragma unroll
        for (int j = 0; j < 4; ++j)
          acc[i][j] = fmaf(av[i], bb[j], acc[i][j]);
    }
    __syncthreads();
  }
#pragma unroll
  for (int i = 0; i < 4; ++i) {
    int m = bm + ty * 4 + i;
    float4 o;
    o.x = fmaxf(acc[i][0] + bias[bn + tx * 4 + 0], 0.0f);
    o.y = fmaxf(acc[i][1] + bias[bn + tx * 4 + 1], 0.0f);
    o.z = fmaxf(acc[i][2] + bias[bn + tx * 4 + 2], 0.0f);
    o.w = fmaxf(acc[i][3] + bias[bn + tx * 4 + 3], 0.0f);
    *(float4*)&C[(size_t)m * N + bn + tx * 4] = o;
  }
}

// ---------------- maxpool over Ks consecutive rows ----------------
__global__ __launch_bounds__(256) void k_maxpool(const float* __restrict__ H,
                                                 float* __restrict__ F,
                                                 int S, int Ks, int Nch, int sbase) {
  int t = blockIdx.x * 256 + threadIdx.x;
  if (t >= S * Nch) return;
  int sl = t / Nch, n = t % Nch;
  const float* p = H + (size_t)sl * Ks * Nch + n;
  float m = p[0];
  for (int k = 1; k < Ks; ++k) m = fmaxf(m, p[(size_t)k * Nch]);
  F[(size_t)(sbase + sl) * Nch + n] = m;
}

// ---------------- host ----------------
extern "C" void kernel_launch(void* const* d_in, const int* in_sizes, int n_in,
                              void* d_out, int out_size, void* d_ws, size_t ws_size,
                              hipStream_t stream) {
  (void)n_in; (void)out_size; (void)ws_size;
  const float* pts = (const float*)d_in[0];
  const float* prop = (const float*)d_in[1];

  // inputs may arrive in dict order (w0,b0,w1,b1,w2,b2) or signature order (w0,w1,w2,b0,b1,b2)
  bool dict_order = (in_sizes[3] == 64);
  const float *w[3][3], *b[3][3];
  for (int g = 0; g < 3; ++g)
    for (int l = 0; l < 3; ++l) {
      int base = 2 + g * 6;
      int wi = dict_order ? (base + l * 2) : (base + l);
      int bi = dict_order ? (base + l * 2 + 1) : (base + 3 + l);
      w[g][l] = (const float*)d_in[wi];
      b[g][l] = (const float*)d_in[bi];
    }

  ull* slots = (ull*)d_ws;                   // 2 x 8 x 4 u64 = 512 B (8B aligned)
  float* xx = (float*)(slots + 64);
  float* xy = xx + N_PTS;
  float* xz = xy + N_PTS;
  float* x1x = xz + N_PTS;
  float* x1y = x1x + NP1;
  float* x1z = x1y + NP1;
  float* x2x = x1z + NP1;
  float* x2y = x2x + NP2;
  float* x2z = x2y + NP2;
  int* gidx1 = (int*)(x2z + NP2);            // 2048*32
  int* gidx2 = gidx1 + NP1 * NSAMP1;         // 512*64
  float* f1 = (float*)(gidx2 + NP2 * NSAMP2);// 2048*128
  float* f2 = f1 + NP1 * 128;                // 512*256
  float* Xp = f2 + NP2 * 256;                // 8192*131 pool (also 8192*15, 512*259)
  float* Ha = Xp + 8192 * 131;               // 8192*128 pool
  float* Hb = Ha + 8192 * 128;               // 8192*128 pool
  float* Hc = Hb + 8192 * 128;               // 8192*256 pool (also 512*1024)

  const float R2A = (float)(0.4 * 0.4);  // f32 of python-f64 product: 1 ulp below 0.4f*0.4f
  const float R2B = (float)(0.8 * 0.8);

  k_prep<<<128, 256, 0, stream>>>(pts, prop, xx, xy, xz, slots);
  k_fps1<<<F1B, F1T, 0, stream>>>(xx, xy, xz, slots, x1x, x1y, x1z);
  k_fps2<<<1, F2T, 0, stream>>>(x1x, x1y, x1z, x2x, x2y, x2z);
  k_ballq<<<512, 256, 0, stream>>>(xx, xy, xz, N_PTS, x1x, x1y, x1z, NP1, R2A, NSAMP1, gidx1);
  k_ballq<<<128, 256, 0, stream>>>(x1x, x1y, x1z, NP1, x2x, x2y, x2z, NP2, R2B, NSAMP2, gidx2);

  // SA1: 65536 rows in 8 chunks of 8192 (s-chunks of 256)
  for (int ch = 0; ch < 8; ++ch) {
    int rbase = ch * 8192;
    k_gather1<<<32, 256, 0, stream>>>(pts, prop, xx, xy, xz, x1x, x1y, x1z, gidx1, Xp, rbase);
    k_gemm<<<dim3(1, 128), 256, 0, stream>>>(Xp, w[0][0], b[0][0], Ha, 8192, 64, 15);
    k_gemm<<<dim3(1, 128), 256, 0, stream>>>(Ha, w[0][1], b[0][1], Hb, 8192, 64, 64);
    k_gemm<<<dim3(2, 128), 256, 0, stream>>>(Hb, w[0][2], b[0][2], Hc, 8192, 128, 64);
    k_maxpool<<<128, 256, 0, stream>>>(Hc, f1, 256, 32, 128, ch * 256);
  }

  // SA2: 32768 rows in 4 chunks of 8192 (s-chunks of 128)
  for (int ch = 0; ch < 4; ++ch) {
    int rbase = ch * 8192;
    k_gather2<<<(8192 * 131 + 255) / 256, 256, 0, stream>>>(x1x, x1y, x1z, x2x, x2y, x2z,
                                                            gidx2, f1, Xp, rbase);
    k_gemm<<<dim3(2, 128), 256, 0, stream>>>(Xp, w[1][0], b[1][0], Ha, 8192, 128, 131);
    k_gemm<<<dim3(2, 128), 256, 0, stream>>>(Ha, w[1][1], b[1][1], Hb, 8192, 128, 128);
    k_gemm<<<dim3(4, 128), 256, 0, stream>>>(Hb, w[1][2], b[1][2], Hc, 8192, 256, 128);
    k_maxpool<<<128, 256, 0, stream>>>(Hc, f2, 128, 64, 256, ch * 128);
  }

  // SA3
  k_gather3<<<(512 * 259 + 255) / 256, 256, 0, stream>>>(x2x, x2y, x2z, f2, Xp);
  k_gemm<<<dim3(4, 8), 256, 0, stream>>>(Xp, w[2][0], b[2][0], Ha, 512, 256, 259);
  k_gemm<<<dim3(8, 8), 256, 0, stream>>>(Ha, w[2][1], b[2][1], Hb, 512, 512, 256);
  k_gemm<<<dim3(16, 8), 256, 0, stream>>>(Hb, w[2][2], b[2][2], Hc, 512, 1024, 512);
  k_maxpool<<<4, 256, 0, stream>>>(Hc, (float*)d_out, 1, 512, 1024, 0);
}